// Round 1
// baseline (601.555 us; speedup 1.0000x reference)
//
#include <hip/hip_runtime.h>
#include <stdint.h>

#define TOKENS 8192
#define DIM    1024
#define NEXP   8
#define NASSIGN (TOKENS*2)

// ---- control block indices (ints) ----
#define C_CNT   0    // 8: per-expert token counts
#define C_FILL  8    // 8: atomic fill cursors
#define C_ROW   16   // 9: per-expert row prefix (row_start), [8]=16384
#define C_TILE  25   // 9: per-expert m-tile prefix
#define C_TOTAL 34   // total m-tiles

// ---- workspace layout (bytes) ----
#define WS_CTRL  0
#define WS_TOPE  1024
#define WS_TOPW  (WS_TOPE + NASSIGN*4)
#define WS_PTOK  (WS_TOPW + NASSIGN*4)
#define WS_PW    (WS_PTOK + NASSIGN*4)
#define WS_XB    (WS_PW   + NASSIGN*4)                 // 263168, 256-aligned
#define WS_W1T   (WS_XB  + (size_t)TOKENS*DIM*2)
#define WS_W2T   (WS_W1T + (size_t)NEXP*DIM*DIM*2)
#define WS_H     (WS_W2T + (size_t)NEXP*DIM*DIM*2)
// total = WS_H + 16384*1024*2  ~= 84.2 MB

typedef __attribute__((ext_vector_type(8))) short short8;
typedef __attribute__((ext_vector_type(4))) float floatx4;

__device__ __forceinline__ uint32_t bfr(float f) {   // fp32 -> bf16 bits, RNE
  uint32_t v = __float_as_uint(f);
  return (v + 0x7FFFu + ((v >> 16) & 1u)) >> 16;
}

__device__ __forceinline__ void load_lds16(const void* g, void* l) {
  // async global->LDS, 16B per lane; LDS dst = wave-uniform base + lane*16
  __builtin_amdgcn_global_load_lds(
      (const __attribute__((address_space(1))) uint32_t*)g,
      (__attribute__((address_space(3))) uint32_t*)l, 16, 0, 0);
}

// ---------------- conversion kernels ----------------
__global__ void convx_kernel(const float4* __restrict__ x, uint4* __restrict__ xb) {
  int i = blockIdx.x * blockDim.x + threadIdx.x;   // 1,048,576 groups of 8 elems
  float4 a = x[2*i], b = x[2*i+1];
  uint4 o;
  o.x = bfr(a.x) | (bfr(a.y) << 16);
  o.y = bfr(a.z) | (bfr(a.w) << 16);
  o.z = bfr(b.x) | (bfr(b.y) << 16);
  o.w = bfr(b.z) | (bfr(b.w) << 16);
  xb[i] = o;
}

// transpose+convert: WT[e][f][d] = bf16(W[e][d][f]); 16 matrices (8 W1 + 8 W2)
__global__ void convw_kernel(const float* __restrict__ W1, const float* __restrict__ W2,
                             uint16_t* __restrict__ W1T, uint16_t* __restrict__ W2T) {
  __shared__ uint16_t tile[64][65];
  int m = blockIdx.z;
  const float* src = (m < 8) ? (W1 + (size_t)m*DIM*DIM) : (W2 + (size_t)(m-8)*DIM*DIM);
  uint16_t*    dst = (m < 8) ? (W1T + (size_t)m*DIM*DIM) : (W2T + (size_t)(m-8)*DIM*DIM);
  int d0 = blockIdx.y * 64, f0 = blockIdx.x * 64;
  int t = threadIdx.x;
  int col = t & 63, rb = (t >> 6) * 16;
  #pragma unroll
  for (int i = 0; i < 16; i++) {
    int dr = rb + i;
    tile[dr][col] = (uint16_t)bfr(src[(size_t)(d0+dr)*DIM + f0 + col]);
  }
  __syncthreads();
  #pragma unroll
  for (int i = 0; i < 16; i++) {
    int fr = rb + i;
    dst[(size_t)(f0+fr)*DIM + d0 + col] = tile[col][fr];
  }
}

// ---------------- gating: 1 wave per token ----------------
__global__ void gating_kernel(const float* __restrict__ x, const float* __restrict__ Wg,
                              const float* __restrict__ bg, float* __restrict__ gate_out,
                              int* __restrict__ top_e, float* __restrict__ top_w,
                              int* __restrict__ ctrl) {
  int gid = blockIdx.x * blockDim.x + threadIdx.x;
  int tok = gid >> 6;
  int lane = threadIdx.x & 63;
  if (tok >= TOKENS) return;
  const float4* xr = (const float4*)(x + (size_t)tok * DIM);
  float acc[NEXP];
  #pragma unroll
  for (int e = 0; e < NEXP; e++) acc[e] = 0.f;
  #pragma unroll
  for (int c = 0; c < 4; c++) {
    float4 xv = xr[c*64 + lane];
    int d0 = (c*64 + lane) * 4;
    #pragma unroll
    for (int j = 0; j < 4; j++) {
      float xs = (j==0)?xv.x:(j==1)?xv.y:(j==2)?xv.z:xv.w;
      const float* wrow = Wg + (size_t)(d0 + j) * NEXP;
      #pragma unroll
      for (int e = 0; e < NEXP; e++) acc[e] += xs * wrow[e];
    }
  }
  #pragma unroll
  for (int off = 32; off > 0; off >>= 1) {
    #pragma unroll
    for (int e = 0; e < NEXP; e++) acc[e] += __shfl_xor(acc[e], off);
  }
  if (lane == 0) {
    float lg[NEXP], p[NEXP];
    float mx = -1e30f;
    #pragma unroll
    for (int e = 0; e < NEXP; e++) { lg[e] = acc[e] + bg[e]; mx = fmaxf(mx, lg[e]); }
    float s = 0.f;
    #pragma unroll
    for (int e = 0; e < NEXP; e++) { p[e] = expf(lg[e] - mx); s += p[e]; }
    float inv = 1.f / s;
    #pragma unroll
    for (int e = 0; e < NEXP; e++) p[e] *= inv;
    float4* go = (float4*)(gate_out + (size_t)tok * NEXP);
    go[0] = make_float4(p[0], p[1], p[2], p[3]);
    go[1] = make_float4(p[4], p[5], p[6], p[7]);
    // top-2 with lowest-index tie-break (matches lax.top_k)
    int i1 = 0;
    #pragma unroll
    for (int e = 1; e < NEXP; e++) if (p[e] > p[i1]) i1 = e;
    int i2 = (i1 == 0) ? 1 : 0;
    #pragma unroll
    for (int e = 0; e < NEXP; e++) if (e != i1 && p[e] > p[i2]) i2 = e;
    float ev = expf(p[i2] - p[i1]);         // softmax over the two probabilities
    float w1 = 1.f / (1.f + ev), w2 = ev / (1.f + ev);
    top_e[2*tok]   = i1; top_e[2*tok+1] = i2;
    top_w[2*tok]   = w1; top_w[2*tok+1] = w2;
    atomicAdd(&ctrl[C_CNT + i1], 1);
    atomicAdd(&ctrl[C_CNT + i2], 1);
  }
}

__global__ void scan_kernel(int* __restrict__ ctrl) {
  if (threadIdx.x == 0) {
    int rs = 0, ts = 0;
    for (int e = 0; e < NEXP; e++) {
      ctrl[C_ROW + e] = rs;
      ctrl[C_TILE + e] = ts;
      ctrl[C_FILL + e] = rs;
      int c = ctrl[C_CNT + e];
      rs += c;
      ts += (c + 127) >> 7;
    }
    ctrl[C_ROW + NEXP] = rs;
    ctrl[C_TILE + NEXP] = ts;
    ctrl[C_TOTAL] = ts;
  }
}

__global__ void scatter_kernel(const int* __restrict__ top_e, const float* __restrict__ top_w,
                               int* __restrict__ ctrl, int* __restrict__ ptok,
                               float* __restrict__ pw) {
  int i = blockIdx.x * blockDim.x + threadIdx.x;
  if (i < NASSIGN) {
    int e = top_e[i];
    int pos = atomicAdd(&ctrl[C_FILL + e], 1);
    ptok[pos] = i >> 1;
    pw[pos] = top_w[i];
  }
}

// ---------------- GEMM1: h = relu(gather(x) @ W1 + b1), bf16 out ----------------
__global__ __launch_bounds__(256, 2) void gemm1_kernel(
    const uint16_t* __restrict__ xb, const uint16_t* __restrict__ w1t,
    const float* __restrict__ b1, const int* __restrict__ ctrl,
    const int* __restrict__ ptok, uint16_t* __restrict__ h) {
  __shared__ __align__(16) uint16_t As[128*32];
  __shared__ __align__(16) uint16_t Bs[128*32];
  int mtile = blockIdx.x;
  if (mtile >= ctrl[C_TOTAL]) return;
  int e = 0;
  #pragma unroll
  for (int k = 1; k < NEXP; k++) if (mtile >= ctrl[C_TILE + k]) e = k;
  int row0 = ctrl[C_ROW + e] + (mtile - ctrl[C_TILE + e]) * 128;
  int rend = ctrl[C_ROW + e + 1];
  int n0 = blockIdx.y * 128;

  int t = threadIdx.x, lane = t & 63, w = t >> 6;
  const uint16_t* gA[2];
  const uint16_t* gB[2];
  #pragma unroll
  for (int i = 0; i < 2; i++) {
    int c = w*128 + i*64 + lane;       // chunk id 0..511 (16B each)
    int row = c >> 2, kc = c & 3;
    int ar = row0 + row; if (ar > NASSIGN-1) ar = NASSIGN-1;
    int tok = ptok[ar];
    gA[i] = xb  + (size_t)tok * DIM + kc*8;
    gB[i] = w1t + (size_t)e*DIM*DIM + (size_t)(n0 + row)*DIM + kc*8;
  }
  floatx4 acc[4][4];
  #pragma unroll
  for (int mi = 0; mi < 4; mi++)
    #pragma unroll
    for (int ni = 0; ni < 4; ni++) acc[mi][ni] = (floatx4)(0.f);

  int wm = w & 1, wn = w >> 1;
  int l15 = lane & 15, lq = lane >> 4;

  for (int kt = 0; kt < DIM/32; kt++) {
    #pragma unroll
    for (int i = 0; i < 2; i++) {
      load_lds16(gA[i], &As[(w*128 + i*64) * 8]);
      load_lds16(gB[i], &Bs[(w*128 + i*64) * 8]);
      gA[i] += 32; gB[i] += 32;
    }
    __syncthreads();
    short8 a[4], b[4];
    #pragma unroll
    for (int mi = 0; mi < 4; mi++)
      a[mi] = *(const short8*)&As[(wm*64 + mi*16 + l15)*32 + lq*8];
    #pragma unroll
    for (int ni = 0; ni < 4; ni++)
      b[ni] = *(const short8*)&Bs[(wn*64 + ni*16 + l15)*32 + lq*8];
    #pragma unroll
    for (int mi = 0; mi < 4; mi++)
      #pragma unroll
      for (int ni = 0; ni < 4; ni++)
        acc[mi][ni] = __builtin_amdgcn_mfma_f32_16x16x32_bf16(a[mi], b[ni], acc[mi][ni], 0, 0, 0);
    __syncthreads();
  }
  // epilogue: bias + relu -> bf16 h
  #pragma unroll
  for (int mi = 0; mi < 4; mi++) {
    #pragma unroll
    for (int r = 0; r < 4; r++) {
      int rt = wm*64 + mi*16 + lq*4 + r;
      int ar = row0 + rt;
      if (ar < rend) {
        #pragma unroll
        for (int ni = 0; ni < 4; ni++) {
          int n = n0 + wn*64 + ni*16 + l15;
          float v = acc[mi][ni][r] + b1[e*DIM + n];
          v = fmaxf(v, 0.f);
          h[(size_t)ar*DIM + n] = (uint16_t)bfr(v);
        }
      }
    }
  }
}

// ---------------- GEMM2: y += w * (h @ W2 + b2), atomic scatter ----------------
__global__ __launch_bounds__(256, 2) void gemm2_kernel(
    const uint16_t* __restrict__ h, const uint16_t* __restrict__ w2t,
    const float* __restrict__ b2, const int* __restrict__ ctrl,
    const int* __restrict__ ptok, const float* __restrict__ pw,
    float* __restrict__ y) {
  __shared__ __align__(16) uint16_t As[128*32];
  __shared__ __align__(16) uint16_t Bs[128*32];
  int mtile = blockIdx.x;
  if (mtile >= ctrl[C_TOTAL]) return;
  int e = 0;
  #pragma unroll
  for (int k = 1; k < NEXP; k++) if (mtile >= ctrl[C_TILE + k]) e = k;
  int row0 = ctrl[C_ROW + e] + (mtile - ctrl[C_TILE + e]) * 128;
  int rend = ctrl[C_ROW + e + 1];
  int n0 = blockIdx.y * 128;

  int t = threadIdx.x, lane = t & 63, w = t >> 6;
  const uint16_t* gA[2];
  const uint16_t* gB[2];
  #pragma unroll
  for (int i = 0; i < 2; i++) {
    int c = w*128 + i*64 + lane;
    int row = c >> 2, kc = c & 3;
    int ar = row0 + row; if (ar > NASSIGN-1) ar = NASSIGN-1;
    gA[i] = h   + (size_t)ar * DIM + kc*8;
    gB[i] = w2t + (size_t)e*DIM*DIM + (size_t)(n0 + row)*DIM + kc*8;
  }
  floatx4 acc[4][4];
  #pragma unroll
  for (int mi = 0; mi < 4; mi++)
    #pragma unroll
    for (int ni = 0; ni < 4; ni++) acc[mi][ni] = (floatx4)(0.f);

  int wm = w & 1, wn = w >> 1;
  int l15 = lane & 15, lq = lane >> 4;

  for (int kt = 0; kt < DIM/32; kt++) {
    #pragma unroll
    for (int i = 0; i < 2; i++) {
      load_lds16(gA[i], &As[(w*128 + i*64) * 8]);
      load_lds16(gB[i], &Bs[(w*128 + i*64) * 8]);
      gA[i] += 32; gB[i] += 32;
    }
    __syncthreads();
    short8 a[4], b[4];
    #pragma unroll
    for (int mi = 0; mi < 4; mi++)
      a[mi] = *(const short8*)&As[(wm*64 + mi*16 + l15)*32 + lq*8];
    #pragma unroll
    for (int ni = 0; ni < 4; ni++)
      b[ni] = *(const short8*)&Bs[(wn*64 + ni*16 + l15)*32 + lq*8];
    #pragma unroll
    for (int mi = 0; mi < 4; mi++)
      #pragma unroll
      for (int ni = 0; ni < 4; ni++)
        acc[mi][ni] = __builtin_amdgcn_mfma_f32_16x16x32_bf16(a[mi], b[ni], acc[mi][ni], 0, 0, 0);
    __syncthreads();
  }
  // epilogue: bias, scale by combine weight, atomic scatter-add into y
  #pragma unroll
  for (int mi = 0; mi < 4; mi++) {
    #pragma unroll
    for (int r = 0; r < 4; r++) {
      int rt = wm*64 + mi*16 + lq*4 + r;
      int ar = row0 + rt;
      if (ar < rend) {
        int tok = ptok[ar];
        float wv = pw[ar];
        #pragma unroll
        for (int ni = 0; ni < 4; ni++) {
          int n = n0 + wn*64 + ni*16 + l15;
          float v = (acc[mi][ni][r] + b2[e*DIM + n]) * wv;
          atomicAdd(&y[(size_t)tok*DIM + n], v);
        }
      }
    }
  }
}

extern "C" void kernel_launch(void* const* d_in, const int* in_sizes, int n_in,
                              void* d_out, int out_size, void* d_ws, size_t ws_size,
                              hipStream_t stream) {
  const float* x  = (const float*)d_in[0];
  const float* Wg = (const float*)d_in[1];
  const float* bg = (const float*)d_in[2];
  const float* W1 = (const float*)d_in[3];
  const float* b1 = (const float*)d_in[4];
  const float* W2 = (const float*)d_in[5];
  const float* b2 = (const float*)d_in[6];
  float* out = (float*)d_out;                      // [y: 8192*1024][gate: 8192*8]
  char* ws = (char*)d_ws;

  int*      ctrl = (int*)(ws + WS_CTRL);
  int*      tope = (int*)(ws + WS_TOPE);
  float*    topw = (float*)(ws + WS_TOPW);
  int*      ptok = (int*)(ws + WS_PTOK);
  float*    pwv  = (float*)(ws + WS_PW);
  uint16_t* xb   = (uint16_t*)(ws + WS_XB);
  uint16_t* w1t  = (uint16_t*)(ws + WS_W1T);
  uint16_t* w2t  = (uint16_t*)(ws + WS_W2T);
  uint16_t* hbuf = (uint16_t*)(ws + WS_H);

  hipMemsetAsync(ctrl, 0, 256, stream);
  hipMemsetAsync(out, 0, (size_t)TOKENS*DIM*sizeof(float), stream);  // y accumulator

  convx_kernel<<<4096, 256, 0, stream>>>((const float4*)x, (uint4*)xb);
  convw_kernel<<<dim3(16,16,16), 256, 0, stream>>>(W1, W2, w1t, w2t);
  gating_kernel<<<2048, 256, 0, stream>>>(x, Wg, bg, out + (size_t)TOKENS*DIM,
                                          tope, topw, ctrl);
  scan_kernel<<<1, 64, 0, stream>>>(ctrl);
  scatter_kernel<<<64, 256, 0, stream>>>(tope, topw, ctrl, ptok, pwv);

  // worst-case m-tiles: sum ceil(cnt_e/128) <= 128 + 8 = 136
  gemm1_kernel<<<dim3(136, 8), 256, 0, stream>>>(xb, w1t, b1, ctrl, ptok, hbuf);
  gemm2_kernel<<<dim3(136, 8), 256, 0, stream>>>(hbuf, w2t, b2, ctrl, ptok, pwv, out);
}

// Round 2
// 528.392 us; speedup vs baseline: 1.1385x; 1.1385x over previous
//
#include <hip/hip_runtime.h>
#include <stdint.h>

#define TOKENS 8192
#define DIM    1024
#define NEXP   8
#define NASSIGN (TOKENS*2)

// ---- control block indices (ints) ----
#define C_CNT   0    // 8: per-expert token counts
#define C_FILL  8    // 8: atomic fill cursors
#define C_ROW   16   // 9: per-expert row prefix (row_start), [8]=16384
#define C_TILE  25   // 9: per-expert m-tile prefix
#define C_TOTAL 34   // total m-tiles

// ---- workspace layout (bytes) ----
#define WS_CTRL  0
#define WS_TOPE  1024
#define WS_TOPW  (WS_TOPE + NASSIGN*4)
#define WS_PTOK  (WS_TOPW + NASSIGN*4)
#define WS_AROW  (WS_PTOK + NASSIGN*4)
#define WS_XB    (WS_AROW + NASSIGN*4)                 // 263168, 256-aligned
#define WS_W1T   (WS_XB  + (size_t)TOKENS*DIM*2)
#define WS_W2T   (WS_W1T + (size_t)NEXP*DIM*DIM*2)
#define WS_H     (WS_W2T + (size_t)NEXP*DIM*DIM*2)
// total = WS_H + 16384*1024*2  ~= 84 MB
// ye (bf16, 16384x1024 = 32 MiB) overlays xb+w1t, both dead by gemm2 time:
#define WS_YE    WS_XB

typedef __attribute__((ext_vector_type(8))) short short8;
typedef __attribute__((ext_vector_type(4))) float floatx4;

__device__ __forceinline__ uint32_t bfr(float f) {   // fp32 -> bf16 bits, RNE
  uint32_t v = __float_as_uint(f);
  return (v + 0x7FFFu + ((v >> 16) & 1u)) >> 16;
}
__device__ __forceinline__ float b2f(uint32_t u) { return __uint_as_float(u << 16); }

__device__ __forceinline__ void load_lds16(const void* g, void* l) {
  __builtin_amdgcn_global_load_lds(
      (const __attribute__((address_space(1))) uint32_t*)g,
      (__attribute__((address_space(3))) uint32_t*)l, 16, 0, 0);
}

// ---------------- fused gating + x->bf16 conversion ----------------
// 1 wave per token, 4 tokens/block. Wg^T staged in LDS once per block.
__global__ __launch_bounds__(256) void gateconv_kernel(
    const float* __restrict__ x, const float* __restrict__ Wg,
    const float* __restrict__ bg, float* __restrict__ gate_out,
    int* __restrict__ top_e, float* __restrict__ top_w,
    int* __restrict__ ctrl, uint16_t* __restrict__ xb) {
  __shared__ float wgs[NEXP * DIM];    // wgs[e*DIM + d] = Wg[d][e], 32 KB
  int t = threadIdx.x;
  #pragma unroll
  for (int k = 0; k < 32; k++) {
    int i = k * 256 + t;               // coalesced read of Wg flat
    float v = Wg[i];
    wgs[(i & 7) * DIM + (i >> 3)] = v;
  }
  __syncthreads();

  int wave = t >> 6, lane = t & 63;
  int tok = blockIdx.x * 4 + wave;
  const float4* xr = (const float4*)(x + (size_t)tok * DIM);
  uint2* xw = (uint2*)(xb + (size_t)tok * DIM);

  float4 acc[NEXP];
  #pragma unroll
  for (int e = 0; e < NEXP; e++) acc[e] = make_float4(0.f, 0.f, 0.f, 0.f);

  #pragma unroll
  for (int c = 0; c < 4; c++) {
    float4 xv = xr[c * 64 + lane];
    uint2 o;
    o.x = bfr(xv.x) | (bfr(xv.y) << 16);
    o.y = bfr(xv.z) | (bfr(xv.w) << 16);
    xw[c * 64 + lane] = o;
    int d0 = (c * 64 + lane) * 4;
    #pragma unroll
    for (int e = 0; e < NEXP; e++) {
      float4 wv = *(const float4*)&wgs[e * DIM + d0];
      acc[e].x = fmaf(xv.x, wv.x, acc[e].x);
      acc[e].y = fmaf(xv.y, wv.y, acc[e].y);
      acc[e].z = fmaf(xv.z, wv.z, acc[e].z);
      acc[e].w = fmaf(xv.w, wv.w, acc[e].w);
    }
  }
  float s[NEXP];
  #pragma unroll
  for (int e = 0; e < NEXP; e++) s[e] = (acc[e].x + acc[e].y) + (acc[e].z + acc[e].w);
  #pragma unroll
  for (int off = 32; off > 0; off >>= 1) {
    #pragma unroll
    for (int e = 0; e < NEXP; e++) s[e] += __shfl_xor(s[e], off);
  }
  if (lane == 0) {
    float lg[NEXP], p[NEXP];
    float mx = -1e30f;
    #pragma unroll
    for (int e = 0; e < NEXP; e++) { lg[e] = s[e] + bg[e]; mx = fmaxf(mx, lg[e]); }
    float sum = 0.f;
    #pragma unroll
    for (int e = 0; e < NEXP; e++) { p[e] = expf(lg[e] - mx); sum += p[e]; }
    float inv = 1.f / sum;
    #pragma unroll
    for (int e = 0; e < NEXP; e++) p[e] *= inv;
    float4* go = (float4*)(gate_out + (size_t)tok * NEXP);
    go[0] = make_float4(p[0], p[1], p[2], p[3]);
    go[1] = make_float4(p[4], p[5], p[6], p[7]);
    int i1 = 0;
    #pragma unroll
    for (int e = 1; e < NEXP; e++) if (p[e] > p[i1]) i1 = e;
    int i2 = (i1 == 0) ? 1 : 0;
    #pragma unroll
    for (int e = 0; e < NEXP; e++) if (e != i1 && p[e] > p[i2]) i2 = e;
    float ev = expf(p[i2] - p[i1]);            // softmax over the two top probs
    float w1 = 1.f / (1.f + ev), w2 = ev / (1.f + ev);
    top_e[2*tok]   = i1; top_e[2*tok+1] = i2;
    top_w[2*tok]   = w1; top_w[2*tok+1] = w2;
    atomicAdd(&ctrl[C_CNT + i1], 1);
    atomicAdd(&ctrl[C_CNT + i2], 1);
  }
}

// transpose+convert: WT[e][f][d] = bf16(W[e][d][f]); 16 matrices (8 W1 + 8 W2)
__global__ void convw_kernel(const float* __restrict__ W1, const float* __restrict__ W2,
                             uint16_t* __restrict__ W1T, uint16_t* __restrict__ W2T) {
  __shared__ uint16_t tile[64][65];
  int m = blockIdx.z;
  const float* src = (m < 8) ? (W1 + (size_t)m*DIM*DIM) : (W2 + (size_t)(m-8)*DIM*DIM);
  uint16_t*    dst = (m < 8) ? (W1T + (size_t)m*DIM*DIM) : (W2T + (size_t)(m-8)*DIM*DIM);
  int d0 = blockIdx.y * 64, f0 = blockIdx.x * 64;
  int t = threadIdx.x;
  int col = t & 63, rb = (t >> 6) * 16;
  #pragma unroll
  for (int i = 0; i < 16; i++) {
    int dr = rb + i;
    tile[dr][col] = (uint16_t)bfr(src[(size_t)(d0+dr)*DIM + f0 + col]);
  }
  __syncthreads();
  #pragma unroll
  for (int i = 0; i < 16; i++) {
    int fr = rb + i;
    dst[(size_t)(f0+fr)*DIM + d0 + col] = tile[col][fr];
  }
}

__global__ void scan_kernel(int* __restrict__ ctrl) {
  if (threadIdx.x == 0) {
    int rs = 0, ts = 0;
    for (int e = 0; e < NEXP; e++) {
      ctrl[C_ROW + e] = rs;
      ctrl[C_TILE + e] = ts;
      ctrl[C_FILL + e] = rs;
      int c = ctrl[C_CNT + e];
      rs += c;
      ts += (c + 127) >> 7;
    }
    ctrl[C_ROW + NEXP] = rs;
    ctrl[C_TILE + NEXP] = ts;
    ctrl[C_TOTAL] = ts;
  }
}

__global__ void scatter_kernel(const int* __restrict__ top_e,
                               int* __restrict__ ctrl, int* __restrict__ ptok,
                               int* __restrict__ arow) {
  int i = blockIdx.x * blockDim.x + threadIdx.x;
  if (i < NASSIGN) {
    int e = top_e[i];
    int pos = atomicAdd(&ctrl[C_FILL + e], 1);
    ptok[pos] = i >> 1;
    arow[i] = pos;          // inverse permutation: assignment -> row
  }
}

// ---------------- GEMM1: h = relu(gather(x) @ W1 + b1), bf16 out ----------------
__global__ __launch_bounds__(256, 2) void gemm1_kernel(
    const uint16_t* __restrict__ xb, const uint16_t* __restrict__ w1t,
    const float* __restrict__ b1, const int* __restrict__ ctrl,
    const int* __restrict__ ptok, uint16_t* __restrict__ h) {
  __shared__ __align__(16) uint16_t As[128*32];
  __shared__ __align__(16) uint16_t Bs[128*32];
  int mtile = blockIdx.x;
  if (mtile >= ctrl[C_TOTAL]) return;
  int e = 0;
  #pragma unroll
  for (int k = 1; k < NEXP; k++) if (mtile >= ctrl[C_TILE + k]) e = k;
  int row0 = ctrl[C_ROW + e] + (mtile - ctrl[C_TILE + e]) * 128;
  int rend = ctrl[C_ROW + e + 1];
  int n0 = blockIdx.y * 128;

  int t = threadIdx.x, lane = t & 63, w = t >> 6;
  const uint16_t* gA[2];
  const uint16_t* gB[2];
  #pragma unroll
  for (int i = 0; i < 2; i++) {
    int c = w*128 + i*64 + lane;       // chunk id 0..511 (16B each)
    int row = c >> 2, kc = c & 3;
    int ar = row0 + row; if (ar > NASSIGN-1) ar = NASSIGN-1;
    int tok = ptok[ar];
    gA[i] = xb  + (size_t)tok * DIM + kc*8;
    gB[i] = w1t + (size_t)e*DIM*DIM + (size_t)(n0 + row)*DIM + kc*8;
  }
  floatx4 acc[4][4];
  #pragma unroll
  for (int mi = 0; mi < 4; mi++)
    #pragma unroll
    for (int ni = 0; ni < 4; ni++) acc[mi][ni] = (floatx4)(0.f);

  int wm = w & 1, wn = w >> 1;
  int l15 = lane & 15, lq = lane >> 4;

  for (int kt = 0; kt < DIM/32; kt++) {
    #pragma unroll
    for (int i = 0; i < 2; i++) {
      load_lds16(gA[i], &As[(w*128 + i*64) * 8]);
      load_lds16(gB[i], &Bs[(w*128 + i*64) * 8]);
      gA[i] += 32; gB[i] += 32;
    }
    __syncthreads();
    short8 a[4], b[4];
    #pragma unroll
    for (int mi = 0; mi < 4; mi++)
      a[mi] = *(const short8*)&As[(wm*64 + mi*16 + l15)*32 + lq*8];
    #pragma unroll
    for (int ni = 0; ni < 4; ni++)
      b[ni] = *(const short8*)&Bs[(wn*64 + ni*16 + l15)*32 + lq*8];
    #pragma unroll
    for (int mi = 0; mi < 4; mi++)
      #pragma unroll
      for (int ni = 0; ni < 4; ni++)
        acc[mi][ni] = __builtin_amdgcn_mfma_f32_16x16x32_bf16(a[mi], b[ni], acc[mi][ni], 0, 0, 0);
    __syncthreads();
  }
  #pragma unroll
  for (int mi = 0; mi < 4; mi++) {
    #pragma unroll
    for (int r = 0; r < 4; r++) {
      int rt = wm*64 + mi*16 + lq*4 + r;
      int ar = row0 + rt;
      if (ar < rend) {
        #pragma unroll
        for (int ni = 0; ni < 4; ni++) {
          int n = n0 + wn*64 + ni*16 + l15;
          float v = acc[mi][ni][r] + b1[e*DIM + n];
          v = fmaxf(v, 0.f);
          h[(size_t)ar*DIM + n] = (uint16_t)bfr(v);
        }
      }
    }
  }
}

// ---------------- GEMM2: ye = h @ W2 + b2, bf16 dense rows (no atomics) ----------------
__global__ __launch_bounds__(256, 2) void gemm2_kernel(
    const uint16_t* __restrict__ h, const uint16_t* __restrict__ w2t,
    const float* __restrict__ b2, const int* __restrict__ ctrl,
    uint16_t* __restrict__ yeb) {
  __shared__ __align__(16) uint16_t As[128*32];
  __shared__ __align__(16) uint16_t Bs[128*32];
  int mtile = blockIdx.x;
  if (mtile >= ctrl[C_TOTAL]) return;
  int e = 0;
  #pragma unroll
  for (int k = 1; k < NEXP; k++) if (mtile >= ctrl[C_TILE + k]) e = k;
  int row0 = ctrl[C_ROW + e] + (mtile - ctrl[C_TILE + e]) * 128;
  int rend = ctrl[C_ROW + e + 1];
  int n0 = blockIdx.y * 128;

  int t = threadIdx.x, lane = t & 63, w = t >> 6;
  const uint16_t* gA[2];
  const uint16_t* gB[2];
  #pragma unroll
  for (int i = 0; i < 2; i++) {
    int c = w*128 + i*64 + lane;
    int row = c >> 2, kc = c & 3;
    int ar = row0 + row; if (ar > NASSIGN-1) ar = NASSIGN-1;
    gA[i] = h   + (size_t)ar * DIM + kc*8;
    gB[i] = w2t + (size_t)e*DIM*DIM + (size_t)(n0 + row)*DIM + kc*8;
  }
  floatx4 acc[4][4];
  #pragma unroll
  for (int mi = 0; mi < 4; mi++)
    #pragma unroll
    for (int ni = 0; ni < 4; ni++) acc[mi][ni] = (floatx4)(0.f);

  int wm = w & 1, wn = w >> 1;
  int l15 = lane & 15, lq = lane >> 4;

  for (int kt = 0; kt < DIM/32; kt++) {
    #pragma unroll
    for (int i = 0; i < 2; i++) {
      load_lds16(gA[i], &As[(w*128 + i*64) * 8]);
      load_lds16(gB[i], &Bs[(w*128 + i*64) * 8]);
      gA[i] += 32; gB[i] += 32;
    }
    __syncthreads();
    short8 a[4], b[4];
    #pragma unroll
    for (int mi = 0; mi < 4; mi++)
      a[mi] = *(const short8*)&As[(wm*64 + mi*16 + l15)*32 + lq*8];
    #pragma unroll
    for (int ni = 0; ni < 4; ni++)
      b[ni] = *(const short8*)&Bs[(wn*64 + ni*16 + l15)*32 + lq*8];
    #pragma unroll
    for (int mi = 0; mi < 4; mi++)
      #pragma unroll
      for (int ni = 0; ni < 4; ni++)
        acc[mi][ni] = __builtin_amdgcn_mfma_f32_16x16x32_bf16(a[mi], b[ni], acc[mi][ni], 0, 0, 0);
    __syncthreads();
  }
  #pragma unroll
  for (int mi = 0; mi < 4; mi++) {
    #pragma unroll
    for (int r = 0; r < 4; r++) {
      int rt = wm*64 + mi*16 + lq*4 + r;
      int ar = row0 + rt;
      if (ar < rend) {
        #pragma unroll
        for (int ni = 0; ni < 4; ni++) {
          int n = n0 + wn*64 + ni*16 + l15;
          float v = acc[mi][ni][r] + b2[e*DIM + n];
          yeb[(size_t)ar*DIM + n] = (uint16_t)bfr(v);
        }
      }
    }
  }
}

// ---------------- combine: y[tok] = w0*ye[r0] + w1*ye[r1] ----------------
__global__ __launch_bounds__(256) void combine_kernel(
    const uint16_t* __restrict__ yeb, const int* __restrict__ arow,
    const float* __restrict__ top_w, float* __restrict__ y) {
  int tok = blockIdx.x, t = threadIdx.x;
  int r0 = arow[2*tok], r1 = arow[2*tok+1];
  float w0 = top_w[2*tok], w1 = top_w[2*tok+1];
  const uint2* a = (const uint2*)(yeb + (size_t)r0 * DIM);
  const uint2* b = (const uint2*)(yeb + (size_t)r1 * DIM);
  uint2 av = a[t], bv = b[t];
  float4 o;
  o.x = w0 * b2f(av.x & 0xFFFFu) + w1 * b2f(bv.x & 0xFFFFu);
  o.y = w0 * b2f(av.x >> 16)     + w1 * b2f(bv.x >> 16);
  o.z = w0 * b2f(av.y & 0xFFFFu) + w1 * b2f(bv.y & 0xFFFFu);
  o.w = w0 * b2f(av.y >> 16)     + w1 * b2f(bv.y >> 16);
  ((float4*)(y + (size_t)tok * DIM))[t] = o;
}

extern "C" void kernel_launch(void* const* d_in, const int* in_sizes, int n_in,
                              void* d_out, int out_size, void* d_ws, size_t ws_size,
                              hipStream_t stream) {
  const float* x  = (const float*)d_in[0];
  const float* Wg = (const float*)d_in[1];
  const float* bg = (const float*)d_in[2];
  const float* W1 = (const float*)d_in[3];
  const float* b1 = (const float*)d_in[4];
  const float* W2 = (const float*)d_in[5];
  const float* b2 = (const float*)d_in[6];
  float* out = (float*)d_out;                      // [y: 8192*1024][gate: 8192*8]
  char* ws = (char*)d_ws;

  int*      ctrl = (int*)(ws + WS_CTRL);
  int*      tope = (int*)(ws + WS_TOPE);
  float*    topw = (float*)(ws + WS_TOPW);
  int*      ptok = (int*)(ws + WS_PTOK);
  int*      arow = (int*)(ws + WS_AROW);
  uint16_t* xb   = (uint16_t*)(ws + WS_XB);
  uint16_t* w1t  = (uint16_t*)(ws + WS_W1T);
  uint16_t* w2t  = (uint16_t*)(ws + WS_W2T);
  uint16_t* hbuf = (uint16_t*)(ws + WS_H);
  uint16_t* yeb  = (uint16_t*)(ws + WS_YE);        // overlays xb+w1t (dead by then)

  hipMemsetAsync(ctrl, 0, 256, stream);

  convw_kernel<<<dim3(16,16,16), 256, 0, stream>>>(W1, W2, w1t, w2t);
  gateconv_kernel<<<2048, 256, 0, stream>>>(x, Wg, bg, out + (size_t)TOKENS*DIM,
                                            tope, topw, ctrl, xb);
  scan_kernel<<<1, 64, 0, stream>>>(ctrl);
  scatter_kernel<<<64, 256, 0, stream>>>(tope, ctrl, ptok, arow);

  // worst-case m-tiles: sum ceil(cnt_e/128) <= 128 + 8 = 136
  gemm1_kernel<<<dim3(136, 8), 256, 0, stream>>>(xb, w1t, b1, ctrl, ptok, hbuf);
  gemm2_kernel<<<dim3(136, 8), 256, 0, stream>>>(hbuf, w2t, b2, ctrl, yeb);
  combine_kernel<<<TOKENS, 256, 0, stream>>>(yeb, arow, topw, out);
}

// Round 3
// 306.997 us; speedup vs baseline: 1.9595x; 1.7212x over previous
//
#include <hip/hip_runtime.h>
#include <stdint.h>

#define TOKENS 8192
#define DIM    1024
#define NEXP   8
#define NASSIGN (TOKENS*2)

// ---- control block indices (ints) ----
#define C_ROW   16   // 9: per-expert row prefix (row_start), [8]=16384
#define C_TILE  25   // 9: per-expert m-tile prefix
#define C_TOTAL 34   // total m-tiles

// ---- workspace layout (bytes) ----
#define WS_CTRL  0
#define WS_TOPE  1024
#define WS_TOPW  (WS_TOPE + NASSIGN*4)
#define WS_PTOK  (WS_TOPW + NASSIGN*4)
#define WS_AROW  (WS_PTOK + NASSIGN*4)
#define WS_XB    (WS_AROW + NASSIGN*4)                 // 263168, 256-aligned
#define WS_W1T   (WS_XB  + (size_t)TOKENS*DIM*2)
#define WS_W2T   (WS_W1T + (size_t)NEXP*DIM*DIM*2)
#define WS_H     (WS_W2T + (size_t)NEXP*DIM*DIM*2)
// total = WS_H + 16384*1024*2  ~= 84 MB
// ye (bf16, 16384x1024 = 32 MiB) overlays xb+w1t, both dead by gemm2 time:
#define WS_YE    WS_XB

#define WGLD (DIM + 4)   // padded LDS row for Wg^T staging (bank-conflict-free)

typedef __attribute__((ext_vector_type(8))) short short8;
typedef __attribute__((ext_vector_type(4))) float floatx4;

__device__ __forceinline__ uint32_t bfr(float f) {   // fp32 -> bf16 bits, RNE
  uint32_t v = __float_as_uint(f);
  return (v + 0x7FFFu + ((v >> 16) & 1u)) >> 16;
}
__device__ __forceinline__ float b2f(uint32_t u) { return __uint_as_float(u << 16); }

__device__ __forceinline__ void load_lds16(const void* g, void* l) {
  __builtin_amdgcn_global_load_lds(
      (const __attribute__((address_space(1))) uint32_t*)g,
      (__attribute__((address_space(3))) uint32_t*)l, 16, 0, 0);
}

// ---------------- fused gating + x->bf16 conversion (NO atomics) ----------------
__global__ __launch_bounds__(256) void gateconv_kernel(
    const float* __restrict__ x, const float* __restrict__ Wg,
    const float* __restrict__ bg, float* __restrict__ gate_out,
    int* __restrict__ top_e, float* __restrict__ top_w,
    uint16_t* __restrict__ xb) {
  __shared__ float wgs[NEXP * WGLD];   // wgs[e*WGLD + d] = Wg[d][e]
  int t = threadIdx.x;
  #pragma unroll
  for (int k = 0; k < 32; k++) {
    int i = k * 256 + t;               // coalesced read of Wg flat
    float v = Wg[i];
    wgs[(i & 7) * WGLD + (i >> 3)] = v;   // bank = 4*(i&7)+(i>>3): 2-way, free
  }
  __syncthreads();

  int wave = t >> 6, lane = t & 63;
  int tok = blockIdx.x * 4 + wave;
  const float4* xr = (const float4*)(x + (size_t)tok * DIM);
  uint2* xw = (uint2*)(xb + (size_t)tok * DIM);

  float4 acc[NEXP];
  #pragma unroll
  for (int e = 0; e < NEXP; e++) acc[e] = make_float4(0.f, 0.f, 0.f, 0.f);

  #pragma unroll
  for (int c = 0; c < 4; c++) {
    float4 xv = xr[c * 64 + lane];
    uint2 o;
    o.x = bfr(xv.x) | (bfr(xv.y) << 16);
    o.y = bfr(xv.z) | (bfr(xv.w) << 16);
    xw[c * 64 + lane] = o;
    int d0 = (c * 64 + lane) * 4;
    #pragma unroll
    for (int e = 0; e < NEXP; e++) {
      float4 wv = *(const float4*)&wgs[e * WGLD + d0];
      acc[e].x = fmaf(xv.x, wv.x, acc[e].x);
      acc[e].y = fmaf(xv.y, wv.y, acc[e].y);
      acc[e].z = fmaf(xv.z, wv.z, acc[e].z);
      acc[e].w = fmaf(xv.w, wv.w, acc[e].w);
    }
  }
  float s[NEXP];
  #pragma unroll
  for (int e = 0; e < NEXP; e++) s[e] = (acc[e].x + acc[e].y) + (acc[e].z + acc[e].w);
  #pragma unroll
  for (int off = 32; off > 0; off >>= 1) {
    #pragma unroll
    for (int e = 0; e < NEXP; e++) s[e] += __shfl_xor(s[e], off);
  }
  if (lane == 0) {
    float lg[NEXP], p[NEXP];
    float mx = -1e30f;
    #pragma unroll
    for (int e = 0; e < NEXP; e++) { lg[e] = s[e] + bg[e]; mx = fmaxf(mx, lg[e]); }
    float sum = 0.f;
    #pragma unroll
    for (int e = 0; e < NEXP; e++) { p[e] = expf(lg[e] - mx); sum += p[e]; }
    float inv = 1.f / sum;
    #pragma unroll
    for (int e = 0; e < NEXP; e++) p[e] *= inv;
    float4* go = (float4*)(gate_out + (size_t)tok * NEXP);
    go[0] = make_float4(p[0], p[1], p[2], p[3]);
    go[1] = make_float4(p[4], p[5], p[6], p[7]);
    int i1 = 0;
    #pragma unroll
    for (int e = 1; e < NEXP; e++) if (p[e] > p[i1]) i1 = e;
    int i2 = (i1 == 0) ? 1 : 0;
    #pragma unroll
    for (int e = 0; e < NEXP; e++) if (e != i1 && p[e] > p[i2]) i2 = e;
    float ev = expf(p[i2] - p[i1]);            // softmax over the two top probs
    float w1 = 1.f / (1.f + ev), w2 = ev / (1.f + ev);
    top_e[2*tok]   = i1; top_e[2*tok+1] = i2;
    top_w[2*tok]   = w1; top_w[2*tok+1] = w2;
  }
}

// transpose+convert: WT[e][f][d] = bf16(W[e][d][f]); 16 matrices (8 W1 + 8 W2)
__global__ void convw_kernel(const float* __restrict__ W1, const float* __restrict__ W2,
                             uint16_t* __restrict__ W1T, uint16_t* __restrict__ W2T) {
  __shared__ uint16_t tile[64][65];
  int m = blockIdx.z;
  const float* src = (m < 8) ? (W1 + (size_t)m*DIM*DIM) : (W2 + (size_t)(m-8)*DIM*DIM);
  uint16_t*    dst = (m < 8) ? (W1T + (size_t)m*DIM*DIM) : (W2T + (size_t)(m-8)*DIM*DIM);
  int d0 = blockIdx.y * 64, f0 = blockIdx.x * 64;
  int t = threadIdx.x;
  int col = t & 63, rb = (t >> 6) * 16;
  #pragma unroll
  for (int i = 0; i < 16; i++) {
    int dr = rb + i;
    tile[dr][col] = (uint16_t)bfr(src[(size_t)(d0+dr)*DIM + f0 + col]);
  }
  __syncthreads();
  #pragma unroll
  for (int i = 0; i < 16; i++) {
    int fr = rb + i;
    dst[(size_t)(f0+fr)*DIM + d0 + col] = tile[col][fr];
  }
}

// ---------------- deterministic routing: histogram + scan + scatter, 1 block ----------------
__global__ __launch_bounds__(1024) void route_kernel(
    const int* __restrict__ top_e, int* __restrict__ ctrl,
    int* __restrict__ ptok, int* __restrict__ arow) {
  __shared__ int sc[NEXP * 1024];      // 32 KB: per-thread per-expert counts -> excl prefix
  __shared__ int scnt[NEXP];           // per-expert totals
  __shared__ int rowstart[NEXP];
  int t = threadIdx.x;
  int e_loc[16];
  int cnt[NEXP];
  #pragma unroll
  for (int e = 0; e < NEXP; e++) cnt[e] = 0;
  #pragma unroll
  for (int j = 0; j < 16; j++) {
    int e = top_e[t * 16 + j];
    e_loc[j] = e;
    cnt[e]++;
  }
  #pragma unroll
  for (int e = 0; e < NEXP; e++) sc[e * 1024 + t] = cnt[e];
  __syncthreads();
  int wave = t >> 6, lane = t & 63;
  if (wave < NEXP) {                   // wave w: exclusive scan of expert w's 1024 counts
    int running = 0;
    for (int chunk = 0; chunk < 16; chunk++) {
      int idx = wave * 1024 + chunk * 64 + lane;
      int v = sc[idx];
      int incl = v;
      #pragma unroll
      for (int off = 1; off < 64; off <<= 1) {
        int u = __shfl_up(incl, off);
        if (lane >= off) incl += u;
      }
      sc[idx] = running + incl - v;    // exclusive prefix
      running += __shfl(incl, 63);
    }
    if (lane == 0) scnt[wave] = running;
  }
  __syncthreads();
  if (t == 0) {
    int rs = 0, ts = 0;
    for (int e = 0; e < NEXP; e++) {
      ctrl[C_ROW + e] = rs;
      ctrl[C_TILE + e] = ts;
      rowstart[e] = rs;
      int c = scnt[e];
      rs += c;
      ts += (c + 127) >> 7;
    }
    ctrl[C_ROW + NEXP] = rs;
    ctrl[C_TILE + NEXP] = ts;
    ctrl[C_TOTAL] = ts;
  }
  __syncthreads();
  int off[NEXP];
  #pragma unroll
  for (int e = 0; e < NEXP; e++) off[e] = rowstart[e] + sc[e * 1024 + t];
  #pragma unroll
  for (int j = 0; j < 16; j++) {
    int i = t * 16 + j;
    int e = e_loc[j];
    int pos = off[e]++;
    ptok[pos] = i >> 1;
    arow[i] = pos;                     // inverse permutation: assignment -> row
  }
}

// ---------------- GEMM1: h = relu(gather(x) @ W1 + b1), bf16 out ----------------
__global__ __launch_bounds__(256, 2) void gemm1_kernel(
    const uint16_t* __restrict__ xb, const uint16_t* __restrict__ w1t,
    const float* __restrict__ b1, const int* __restrict__ ctrl,
    const int* __restrict__ ptok, uint16_t* __restrict__ h) {
  __shared__ __align__(16) uint16_t As[128*32];
  __shared__ __align__(16) uint16_t Bs[128*32];
  int mtile = blockIdx.x;
  if (mtile >= ctrl[C_TOTAL]) return;
  int e = 0;
  #pragma unroll
  for (int k = 1; k < NEXP; k++) if (mtile >= ctrl[C_TILE + k]) e = k;
  int row0 = ctrl[C_ROW + e] + (mtile - ctrl[C_TILE + e]) * 128;
  int rend = ctrl[C_ROW + e + 1];
  int n0 = blockIdx.y * 128;

  int t = threadIdx.x, lane = t & 63, w = t >> 6;
  const uint16_t* gA[2];
  const uint16_t* gB[2];
  #pragma unroll
  for (int i = 0; i < 2; i++) {
    int c = w*128 + i*64 + lane;       // chunk id 0..511 (16B each)
    int row = c >> 2, kc = c & 3;
    int ar = row0 + row; if (ar > NASSIGN-1) ar = NASSIGN-1;
    int tok = ptok[ar];
    gA[i] = xb  + (size_t)tok * DIM + kc*8;
    gB[i] = w1t + (size_t)e*DIM*DIM + (size_t)(n0 + row)*DIM + kc*8;
  }
  floatx4 acc[4][4];
  #pragma unroll
  for (int mi = 0; mi < 4; mi++)
    #pragma unroll
    for (int ni = 0; ni < 4; ni++) acc[mi][ni] = (floatx4)(0.f);

  int wm = w & 1, wn = w >> 1;
  int l15 = lane & 15, lq = lane >> 4;

  for (int kt = 0; kt < DIM/32; kt++) {
    #pragma unroll
    for (int i = 0; i < 2; i++) {
      load_lds16(gA[i], &As[(w*128 + i*64) * 8]);
      load_lds16(gB[i], &Bs[(w*128 + i*64) * 8]);
      gA[i] += 32; gB[i] += 32;
    }
    __syncthreads();
    short8 a[4], b[4];
    #pragma unroll
    for (int mi = 0; mi < 4; mi++)
      a[mi] = *(const short8*)&As[(wm*64 + mi*16 + l15)*32 + lq*8];
    #pragma unroll
    for (int ni = 0; ni < 4; ni++)
      b[ni] = *(const short8*)&Bs[(wn*64 + ni*16 + l15)*32 + lq*8];
    #pragma unroll
    for (int mi = 0; mi < 4; mi++)
      #pragma unroll
      for (int ni = 0; ni < 4; ni++)
        acc[mi][ni] = __builtin_amdgcn_mfma_f32_16x16x32_bf16(a[mi], b[ni], acc[mi][ni], 0, 0, 0);
    __syncthreads();
  }
  #pragma unroll
  for (int mi = 0; mi < 4; mi++) {
    #pragma unroll
    for (int r = 0; r < 4; r++) {
      int rt = wm*64 + mi*16 + lq*4 + r;
      int ar = row0 + rt;
      if (ar < rend) {
        #pragma unroll
        for (int ni = 0; ni < 4; ni++) {
          int n = n0 + wn*64 + ni*16 + l15;
          float v = acc[mi][ni][r] + b1[e*DIM + n];
          v = fmaxf(v, 0.f);
          h[(size_t)ar*DIM + n] = (uint16_t)bfr(v);
        }
      }
    }
  }
}

// ---------------- GEMM2: ye = h @ W2 + b2, bf16 dense rows (no atomics) ----------------
__global__ __launch_bounds__(256, 2) void gemm2_kernel(
    const uint16_t* __restrict__ h, const uint16_t* __restrict__ w2t,
    const float* __restrict__ b2, const int* __restrict__ ctrl,
    uint16_t* __restrict__ yeb) {
  __shared__ __align__(16) uint16_t As[128*32];
  __shared__ __align__(16) uint16_t Bs[128*32];
  int mtile = blockIdx.x;
  if (mtile >= ctrl[C_TOTAL]) return;
  int e = 0;
  #pragma unroll
  for (int k = 1; k < NEXP; k++) if (mtile >= ctrl[C_TILE + k]) e = k;
  int row0 = ctrl[C_ROW + e] + (mtile - ctrl[C_TILE + e]) * 128;
  int rend = ctrl[C_ROW + e + 1];
  int n0 = blockIdx.y * 128;

  int t = threadIdx.x, lane = t & 63, w = t >> 6;
  const uint16_t* gA[2];
  const uint16_t* gB[2];
  #pragma unroll
  for (int i = 0; i < 2; i++) {
    int c = w*128 + i*64 + lane;
    int row = c >> 2, kc = c & 3;
    int ar = row0 + row; if (ar > NASSIGN-1) ar = NASSIGN-1;
    gA[i] = h   + (size_t)ar * DIM + kc*8;
    gB[i] = w2t + (size_t)e*DIM*DIM + (size_t)(n0 + row)*DIM + kc*8;
  }
  floatx4 acc[4][4];
  #pragma unroll
  for (int mi = 0; mi < 4; mi++)
    #pragma unroll
    for (int ni = 0; ni < 4; ni++) acc[mi][ni] = (floatx4)(0.f);

  int wm = w & 1, wn = w >> 1;
  int l15 = lane & 15, lq = lane >> 4;

  for (int kt = 0; kt < DIM/32; kt++) {
    #pragma unroll
    for (int i = 0; i < 2; i++) {
      load_lds16(gA[i], &As[(w*128 + i*64) * 8]);
      load_lds16(gB[i], &Bs[(w*128 + i*64) * 8]);
      gA[i] += 32; gB[i] += 32;
    }
    __syncthreads();
    short8 a[4], b[4];
    #pragma unroll
    for (int mi = 0; mi < 4; mi++)
      a[mi] = *(const short8*)&As[(wm*64 + mi*16 + l15)*32 + lq*8];
    #pragma unroll
    for (int ni = 0; ni < 4; ni++)
      b[ni] = *(const short8*)&Bs[(wn*64 + ni*16 + l15)*32 + lq*8];
    #pragma unroll
    for (int mi = 0; mi < 4; mi++)
      #pragma unroll
      for (int ni = 0; ni < 4; ni++)
        acc[mi][ni] = __builtin_amdgcn_mfma_f32_16x16x32_bf16(a[mi], b[ni], acc[mi][ni], 0, 0, 0);
    __syncthreads();
  }
  #pragma unroll
  for (int mi = 0; mi < 4; mi++) {
    #pragma unroll
    for (int r = 0; r < 4; r++) {
      int rt = wm*64 + mi*16 + lq*4 + r;
      int ar = row0 + rt;
      if (ar < rend) {
        #pragma unroll
        for (int ni = 0; ni < 4; ni++) {
          int n = n0 + wn*64 + ni*16 + l15;
          float v = acc[mi][ni][r] + b2[e*DIM + n];
          yeb[(size_t)ar*DIM + n] = (uint16_t)bfr(v);
        }
      }
    }
  }
}

// ---------------- combine: y[tok] = w0*ye[r0] + w1*ye[r1] ----------------
__global__ __launch_bounds__(256) void combine_kernel(
    const uint16_t* __restrict__ yeb, const int* __restrict__ arow,
    const float* __restrict__ top_w, float* __restrict__ y) {
  int tok = blockIdx.x, t = threadIdx.x;
  int r0 = arow[2*tok], r1 = arow[2*tok+1];
  float w0 = top_w[2*tok], w1 = top_w[2*tok+1];
  const uint2* a = (const uint2*)(yeb + (size_t)r0 * DIM);
  const uint2* b = (const uint2*)(yeb + (size_t)r1 * DIM);
  uint2 av = a[t], bv = b[t];
  float4 o;
  o.x = w0 * b2f(av.x & 0xFFFFu) + w1 * b2f(bv.x & 0xFFFFu);
  o.y = w0 * b2f(av.x >> 16)     + w1 * b2f(bv.x >> 16);
  o.z = w0 * b2f(av.y & 0xFFFFu) + w1 * b2f(bv.y & 0xFFFFu);
  o.w = w0 * b2f(av.y >> 16)     + w1 * b2f(bv.y >> 16);
  ((float4*)(y + (size_t)tok * DIM))[t] = o;
}

extern "C" void kernel_launch(void* const* d_in, const int* in_sizes, int n_in,
                              void* d_out, int out_size, void* d_ws, size_t ws_size,
                              hipStream_t stream) {
  const float* x  = (const float*)d_in[0];
  const float* Wg = (const float*)d_in[1];
  const float* bg = (const float*)d_in[2];
  const float* W1 = (const float*)d_in[3];
  const float* b1 = (const float*)d_in[4];
  const float* W2 = (const float*)d_in[5];
  const float* b2 = (const float*)d_in[6];
  float* out = (float*)d_out;                      // [y: 8192*1024][gate: 8192*8]
  char* ws = (char*)d_ws;

  int*      ctrl = (int*)(ws + WS_CTRL);
  int*      tope = (int*)(ws + WS_TOPE);
  float*    topw = (float*)(ws + WS_TOPW);
  int*      ptok = (int*)(ws + WS_PTOK);
  int*      arow = (int*)(ws + WS_AROW);
  uint16_t* xb   = (uint16_t*)(ws + WS_XB);
  uint16_t* w1t  = (uint16_t*)(ws + WS_W1T);
  uint16_t* w2t  = (uint16_t*)(ws + WS_W2T);
  uint16_t* hbuf = (uint16_t*)(ws + WS_H);
  uint16_t* yeb  = (uint16_t*)(ws + WS_YE);        // overlays xb+w1t (dead by then)

  convw_kernel<<<dim3(16,16,16), 256, 0, stream>>>(W1, W2, w1t, w2t);
  gateconv_kernel<<<2048, 256, 0, stream>>>(x, Wg, bg, out + (size_t)TOKENS*DIM,
                                            tope, topw, xb);
  route_kernel<<<1, 1024, 0, stream>>>(tope, ctrl, ptok, arow);

  // worst-case m-tiles: sum ceil(cnt_e/128) <= 128 + 8 = 136
  gemm1_kernel<<<dim3(136, 8), 256, 0, stream>>>(xb, w1t, b1, ctrl, ptok, hbuf);
  gemm2_kernel<<<dim3(136, 8), 256, 0, stream>>>(hbuf, w2t, b2, ctrl, yeb);
  combine_kernel<<<TOKENS, 256, 0, stream>>>(yeb, arow, topw, out);
}

// Round 4
// 293.481 us; speedup vs baseline: 2.0497x; 1.0461x over previous
//
#include <hip/hip_runtime.h>
#include <stdint.h>

#define TOKENS 8192
#define DIM    1024
#define NEXP   8
#define NASSIGN (TOKENS*2)
#define BK     64          // K-depth of LDS tile (32 KB total LDS)

// ---- control block indices (ints) ----
#define C_ROW   16   // 9: per-expert row prefix (row_start), [8]=16384
#define C_TILE  25   // 9: per-expert m-tile prefix
#define C_TOTAL 34   // total m-tiles

// ---- workspace layout (bytes) ----
#define WS_CTRL  0
#define WS_TOPE  1024
#define WS_TOPW  (WS_TOPE + NASSIGN*4)
#define WS_PTOK  (WS_TOPW + NASSIGN*4)
#define WS_AROW  (WS_PTOK + NASSIGN*4)
#define WS_XB    (WS_AROW + NASSIGN*4)                 // 263168, 256-aligned
#define WS_W1T   (WS_XB  + (size_t)TOKENS*DIM*2)
#define WS_W2T   (WS_W1T + (size_t)NEXP*DIM*DIM*2)
#define WS_H     (WS_W2T + (size_t)NEXP*DIM*DIM*2)
// ye (bf16, 16384x1024 = 32 MiB) overlays xb+w1t, both dead by gemm2 time:
#define WS_YE    WS_XB

#define WGLD (DIM + 4)   // padded LDS row for Wg^T staging (bank-conflict-free)

typedef __attribute__((ext_vector_type(8))) short short8;
typedef __attribute__((ext_vector_type(4))) float floatx4;

__device__ __forceinline__ uint32_t bfr(float f) {   // fp32 -> bf16 bits, RNE
  uint32_t v = __float_as_uint(f);
  return (v + 0x7FFFu + ((v >> 16) & 1u)) >> 16;
}
__device__ __forceinline__ float b2f(uint32_t u) { return __uint_as_float(u << 16); }

__device__ __forceinline__ void load_lds16(const void* g, void* l) {
  __builtin_amdgcn_global_load_lds(
      (const __attribute__((address_space(1))) uint32_t*)g,
      (__attribute__((address_space(3))) uint32_t*)l, 16, 0, 0);
}

// ---------------- fused gating + x->bf16 conversion (NO atomics) ----------------
__global__ __launch_bounds__(256) void gateconv_kernel(
    const float* __restrict__ x, const float* __restrict__ Wg,
    const float* __restrict__ bg, float* __restrict__ gate_out,
    int* __restrict__ top_e, float* __restrict__ top_w,
    uint16_t* __restrict__ xb) {
  __shared__ float wgs[NEXP * WGLD];   // wgs[e*WGLD + d] = Wg[d][e]
  int t = threadIdx.x;
  #pragma unroll
  for (int k = 0; k < 32; k++) {
    int i = k * 256 + t;               // coalesced read of Wg flat
    float v = Wg[i];
    wgs[(i & 7) * WGLD + (i >> 3)] = v;   // bank = 4*(i&7)+(i>>3): 2-way, free
  }
  __syncthreads();

  int wave = t >> 6, lane = t & 63;
  int tok = blockIdx.x * 4 + wave;
  const float4* xr = (const float4*)(x + (size_t)tok * DIM);
  uint2* xw = (uint2*)(xb + (size_t)tok * DIM);

  float4 acc[NEXP];
  #pragma unroll
  for (int e = 0; e < NEXP; e++) acc[e] = make_float4(0.f, 0.f, 0.f, 0.f);

  #pragma unroll
  for (int c = 0; c < 4; c++) {
    float4 xv = xr[c * 64 + lane];
    uint2 o;
    o.x = bfr(xv.x) | (bfr(xv.y) << 16);
    o.y = bfr(xv.z) | (bfr(xv.w) << 16);
    xw[c * 64 + lane] = o;
    int d0 = (c * 64 + lane) * 4;
    #pragma unroll
    for (int e = 0; e < NEXP; e++) {
      float4 wv = *(const float4*)&wgs[e * WGLD + d0];
      acc[e].x = fmaf(xv.x, wv.x, acc[e].x);
      acc[e].y = fmaf(xv.y, wv.y, acc[e].y);
      acc[e].z = fmaf(xv.z, wv.z, acc[e].z);
      acc[e].w = fmaf(xv.w, wv.w, acc[e].w);
    }
  }
  float s[NEXP];
  #pragma unroll
  for (int e = 0; e < NEXP; e++) s[e] = (acc[e].x + acc[e].y) + (acc[e].z + acc[e].w);
  #pragma unroll
  for (int off = 32; off > 0; off >>= 1) {
    #pragma unroll
    for (int e = 0; e < NEXP; e++) s[e] += __shfl_xor(s[e], off);
  }
  if (lane == 0) {
    float lg[NEXP], p[NEXP];
    float mx = -1e30f;
    #pragma unroll
    for (int e = 0; e < NEXP; e++) { lg[e] = s[e] + bg[e]; mx = fmaxf(mx, lg[e]); }
    float sum = 0.f;
    #pragma unroll
    for (int e = 0; e < NEXP; e++) { p[e] = expf(lg[e] - mx); sum += p[e]; }
    float inv = 1.f / sum;
    #pragma unroll
    for (int e = 0; e < NEXP; e++) p[e] *= inv;
    float4* go = (float4*)(gate_out + (size_t)tok * NEXP);
    go[0] = make_float4(p[0], p[1], p[2], p[3]);
    go[1] = make_float4(p[4], p[5], p[6], p[7]);
    int i1 = 0;
    #pragma unroll
    for (int e = 1; e < NEXP; e++) if (p[e] > p[i1]) i1 = e;
    int i2 = (i1 == 0) ? 1 : 0;
    #pragma unroll
    for (int e = 0; e < NEXP; e++) if (e != i1 && p[e] > p[i2]) i2 = e;
    float ev = expf(p[i2] - p[i1]);            // softmax over the two top probs
    float w1 = 1.f / (1.f + ev), w2 = ev / (1.f + ev);
    top_e[2*tok]   = i1; top_e[2*tok+1] = i2;
    top_w[2*tok]   = w1; top_w[2*tok+1] = w2;
  }
}

// transpose+convert: WT[e][f][d] = bf16(W[e][d][f]); 16 matrices (8 W1 + 8 W2)
__global__ void convw_kernel(const float* __restrict__ W1, const float* __restrict__ W2,
                             uint16_t* __restrict__ W1T, uint16_t* __restrict__ W2T) {
  __shared__ uint16_t tile[64][68];
  int m = blockIdx.z;
  const float* src = (m < 8) ? (W1 + (size_t)m*DIM*DIM) : (W2 + (size_t)(m-8)*DIM*DIM);
  uint16_t*    dst = (m < 8) ? (W1T + (size_t)m*DIM*DIM) : (W2T + (size_t)(m-8)*DIM*DIM);
  int d0 = blockIdx.y * 64, f0 = blockIdx.x * 64;
  int t = threadIdx.x;
  int col = t & 63, rb = (t >> 6) * 16;
  #pragma unroll
  for (int i = 0; i < 16; i++) {
    int dr = rb + i;
    tile[dr][col] = (uint16_t)bfr(src[(size_t)(d0+dr)*DIM + f0 + col]);
  }
  __syncthreads();
  int dg = t & 15, frb = t >> 4;       // 4 bf16 along d per thread, 16 f-rows/pass
  #pragma unroll
  for (int i = 0; i < 4; i++) {
    int fr = frb + i * 16;
    uint32_t b0 = tile[dg*4+0][fr], b1 = tile[dg*4+1][fr];
    uint32_t b2 = tile[dg*4+2][fr], b3 = tile[dg*4+3][fr];
    uint2 v;
    v.x = b0 | (b1 << 16);
    v.y = b2 | (b3 << 16);
    *(uint2*)&dst[(size_t)(f0+fr)*DIM + d0 + dg*4] = v;
  }
}

// ---------------- deterministic routing: histogram + scan + scatter, 1 block ----------------
__global__ __launch_bounds__(1024) void route_kernel(
    const int* __restrict__ top_e, int* __restrict__ ctrl,
    int* __restrict__ ptok, int* __restrict__ arow) {
  __shared__ int sc[NEXP * 1024];      // 32 KB: per-thread per-expert counts -> excl prefix
  __shared__ int scnt[NEXP];           // per-expert totals
  __shared__ int rowstart[NEXP];
  int t = threadIdx.x;
  int e_loc[16];
  int cnt[NEXP];
  #pragma unroll
  for (int e = 0; e < NEXP; e++) cnt[e] = 0;
  #pragma unroll
  for (int j = 0; j < 16; j++) {
    int e = top_e[t * 16 + j];
    e_loc[j] = e;
    cnt[e]++;
  }
  #pragma unroll
  for (int e = 0; e < NEXP; e++) sc[e * 1024 + t] = cnt[e];
  __syncthreads();
  int wave = t >> 6, lane = t & 63;
  if (wave < NEXP) {                   // wave w: exclusive scan of expert w's 1024 counts
    int running = 0;
    for (int chunk = 0; chunk < 16; chunk++) {
      int idx = wave * 1024 + chunk * 64 + lane;
      int v = sc[idx];
      int incl = v;
      #pragma unroll
      for (int off = 1; off < 64; off <<= 1) {
        int u = __shfl_up(incl, off);
        if (lane >= off) incl += u;
      }
      sc[idx] = running + incl - v;    // exclusive prefix
      running += __shfl(incl, 63);
    }
    if (lane == 0) scnt[wave] = running;
  }
  __syncthreads();
  if (t == 0) {
    int rs = 0, ts = 0;
    for (int e = 0; e < NEXP; e++) {
      ctrl[C_ROW + e] = rs;
      ctrl[C_TILE + e] = ts;
      rowstart[e] = rs;
      int c = scnt[e];
      rs += c;
      ts += (c + 127) >> 7;
    }
    ctrl[C_ROW + NEXP] = rs;
    ctrl[C_TILE + NEXP] = ts;
    ctrl[C_TOTAL] = ts;
  }
  __syncthreads();
  int off[NEXP];
  #pragma unroll
  for (int e = 0; e < NEXP; e++) off[e] = rowstart[e] + sc[e * 1024 + t];
  #pragma unroll
  for (int j = 0; j < 16; j++) {
    int i = t * 16 + j;
    int e = e_loc[j];
    int pos = off[e]++;
    ptok[pos] = i >> 1;
    arow[i] = pos;                     // inverse permutation: assignment -> row
  }
}

// ---------------- GEMM1: h = relu(gather(x) @ W1 + b1), bf16 out ----------------
// 1-D grid: n_idx = blockIdx.x & 7 (XCD-resident B column), mtile = blockIdx.x >> 3.
// LDS tiles 128xBK with XOR swizzle chunk^=(row&7) folded into global source addr.
__global__ __launch_bounds__(256, 2) void gemm1_kernel(
    const uint16_t* __restrict__ xb, const uint16_t* __restrict__ w1t,
    const float* __restrict__ b1, const int* __restrict__ ctrl,
    const int* __restrict__ ptok, uint16_t* __restrict__ h) {
  __shared__ __align__(16) uint16_t As[128*BK];
  __shared__ __align__(16) uint16_t Bs[128*BK];
  int mtile = blockIdx.x >> 3;
  if (mtile >= ctrl[C_TOTAL]) return;
  int n0 = (blockIdx.x & 7) * 128;
  int e = 0;
  #pragma unroll
  for (int k = 1; k < NEXP; k++) if (mtile >= ctrl[C_TILE + k]) e = k;
  int row0 = ctrl[C_ROW + e] + (mtile - ctrl[C_TILE + e]) * 128;
  int rend = ctrl[C_ROW + e + 1];

  int t = threadIdx.x, lane = t & 63, w = t >> 6;
  const uint16_t* gA[4];
  const uint16_t* gB[4];
  #pragma unroll
  for (int i = 0; i < 4; i++) {
    int s = i * 256 + t;               // LDS slot (16B units), 1024 per matrix
    int row = s >> 3, cs = s & 7;
    int gc = cs ^ (row & 7);           // inverse XOR swizzle applied at the source
    int ar = row0 + row; if (ar > NASSIGN-1) ar = NASSIGN-1;
    int tok = ptok[ar];
    gA[i] = xb  + (size_t)tok * DIM + gc*8;
    gB[i] = w1t + (size_t)e*DIM*DIM + (size_t)(n0 + row)*DIM + gc*8;
  }
  floatx4 acc[4][4];
  #pragma unroll
  for (int mi = 0; mi < 4; mi++)
    #pragma unroll
    for (int ni = 0; ni < 4; ni++) acc[mi][ni] = (floatx4)(0.f);

  int wm = w & 1, wn = w >> 1;
  int l15 = lane & 15, lq = lane >> 4;

  for (int kt = 0; kt < DIM/BK; kt++) {
    #pragma unroll
    for (int i = 0; i < 4; i++) {
      load_lds16(gA[i], &As[(i*256 + t) * 8]);
      load_lds16(gB[i], &Bs[(i*256 + t) * 8]);
      gA[i] += BK; gB[i] += BK;
    }
    __syncthreads();
    #pragma unroll
    for (int ks = 0; ks < 2; ks++) {
      short8 a[4], b[4];
      #pragma unroll
      for (int mi = 0; mi < 4; mi++) {
        int row = wm*64 + mi*16 + l15;
        int slot = (ks*4 + lq) ^ (row & 7);
        a[mi] = *(const short8*)&As[row*BK + slot*8];
      }
      #pragma unroll
      for (int ni = 0; ni < 4; ni++) {
        int row = wn*64 + ni*16 + l15;
        int slot = (ks*4 + lq) ^ (row & 7);
        b[ni] = *(const short8*)&Bs[row*BK + slot*8];
      }
      #pragma unroll
      for (int mi = 0; mi < 4; mi++)
        #pragma unroll
        for (int ni = 0; ni < 4; ni++)
          acc[mi][ni] = __builtin_amdgcn_mfma_f32_16x16x32_bf16(a[mi], b[ni], acc[mi][ni], 0, 0, 0);
    }
    __syncthreads();
  }
  #pragma unroll
  for (int mi = 0; mi < 4; mi++) {
    #pragma unroll
    for (int r = 0; r < 4; r++) {
      int rt = wm*64 + mi*16 + lq*4 + r;
      int ar = row0 + rt;
      if (ar < rend) {
        #pragma unroll
        for (int ni = 0; ni < 4; ni++) {
          int n = n0 + wn*64 + ni*16 + l15;
          float v = acc[mi][ni][r] + b1[e*DIM + n];
          v = fmaxf(v, 0.f);
          h[(size_t)ar*DIM + n] = (uint16_t)bfr(v);
        }
      }
    }
  }
}

// ---------------- GEMM2: ye = h @ W2 + b2, bf16 dense rows (no atomics) ----------------
__global__ __launch_bounds__(256, 2) void gemm2_kernel(
    const uint16_t* __restrict__ h, const uint16_t* __restrict__ w2t,
    const float* __restrict__ b2, const int* __restrict__ ctrl,
    uint16_t* __restrict__ yeb) {
  __shared__ __align__(16) uint16_t As[128*BK];
  __shared__ __align__(16) uint16_t Bs[128*BK];
  int mtile = blockIdx.x >> 3;
  if (mtile >= ctrl[C_TOTAL]) return;
  int n0 = (blockIdx.x & 7) * 128;
  int e = 0;
  #pragma unroll
  for (int k = 1; k < NEXP; k++) if (mtile >= ctrl[C_TILE + k]) e = k;
  int row0 = ctrl[C_ROW + e] + (mtile - ctrl[C_TILE + e]) * 128;
  int rend = ctrl[C_ROW + e + 1];

  int t = threadIdx.x, lane = t & 63, w = t >> 6;
  const uint16_t* gA[4];
  const uint16_t* gB[4];
  #pragma unroll
  for (int i = 0; i < 4; i++) {
    int s = i * 256 + t;
    int row = s >> 3, cs = s & 7;
    int gc = cs ^ (row & 7);
    int ar = row0 + row; if (ar > NASSIGN-1) ar = NASSIGN-1;
    gA[i] = h   + (size_t)ar * DIM + gc*8;
    gB[i] = w2t + (size_t)e*DIM*DIM + (size_t)(n0 + row)*DIM + gc*8;
  }
  floatx4 acc[4][4];
  #pragma unroll
  for (int mi = 0; mi < 4; mi++)
    #pragma unroll
    for (int ni = 0; ni < 4; ni++) acc[mi][ni] = (floatx4)(0.f);

  int wm = w & 1, wn = w >> 1;
  int l15 = lane & 15, lq = lane >> 4;

  for (int kt = 0; kt < DIM/BK; kt++) {
    #pragma unroll
    for (int i = 0; i < 4; i++) {
      load_lds16(gA[i], &As[(i*256 + t) * 8]);
      load_lds16(gB[i], &Bs[(i*256 + t) * 8]);
      gA[i] += BK; gB[i] += BK;
    }
    __syncthreads();
    #pragma unroll
    for (int ks = 0; ks < 2; ks++) {
      short8 a[4], b[4];
      #pragma unroll
      for (int mi = 0; mi < 4; mi++) {
        int row = wm*64 + mi*16 + l15;
        int slot = (ks*4 + lq) ^ (row & 7);
        a[mi] = *(const short8*)&As[row*BK + slot*8];
      }
      #pragma unroll
      for (int ni = 0; ni < 4; ni++) {
        int row = wn*64 + ni*16 + l15;
        int slot = (ks*4 + lq) ^ (row & 7);
        b[ni] = *(const short8*)&Bs[row*BK + slot*8];
      }
      #pragma unroll
      for (int mi = 0; mi < 4; mi++)
        #pragma unroll
        for (int ni = 0; ni < 4; ni++)
          acc[mi][ni] = __builtin_amdgcn_mfma_f32_16x16x32_bf16(a[mi], b[ni], acc[mi][ni], 0, 0, 0);
    }
    __syncthreads();
  }
  #pragma unroll
  for (int mi = 0; mi < 4; mi++) {
    #pragma unroll
    for (int r = 0; r < 4; r++) {
      int rt = wm*64 + mi*16 + lq*4 + r;
      int ar = row0 + rt;
      if (ar < rend) {
        #pragma unroll
        for (int ni = 0; ni < 4; ni++) {
          int n = n0 + wn*64 + ni*16 + l15;
          float v = acc[mi][ni][r] + b2[e*DIM + n];
          yeb[(size_t)ar*DIM + n] = (uint16_t)bfr(v);
        }
      }
    }
  }
}

// ---------------- combine: y[tok] = w0*ye[r0] + w1*ye[r1] ----------------
__global__ __launch_bounds__(256) void combine_kernel(
    const uint16_t* __restrict__ yeb, const int* __restrict__ arow,
    const float* __restrict__ top_w, float* __restrict__ y) {
  int tok = blockIdx.x, t = threadIdx.x;
  int r0 = arow[2*tok], r1 = arow[2*tok+1];
  float w0 = top_w[2*tok], w1 = top_w[2*tok+1];
  const uint2* a = (const uint2*)(yeb + (size_t)r0 * DIM);
  const uint2* b = (const uint2*)(yeb + (size_t)r1 * DIM);
  uint2 av = a[t], bv = b[t];
  float4 o;
  o.x = w0 * b2f(av.x & 0xFFFFu) + w1 * b2f(bv.x & 0xFFFFu);
  o.y = w0 * b2f(av.x >> 16)     + w1 * b2f(bv.x >> 16);
  o.z = w0 * b2f(av.y & 0xFFFFu) + w1 * b2f(bv.y & 0xFFFFu);
  o.w = w0 * b2f(av.y >> 16)     + w1 * b2f(bv.y >> 16);
  ((float4*)(y + (size_t)tok * DIM))[t] = o;
}

extern "C" void kernel_launch(void* const* d_in, const int* in_sizes, int n_in,
                              void* d_out, int out_size, void* d_ws, size_t ws_size,
                              hipStream_t stream) {
  const float* x  = (const float*)d_in[0];
  const float* Wg = (const float*)d_in[1];
  const float* bg = (const float*)d_in[2];
  const float* W1 = (const float*)d_in[3];
  const float* b1 = (const float*)d_in[4];
  const float* W2 = (const float*)d_in[5];
  const float* b2 = (const float*)d_in[6];
  float* out = (float*)d_out;                      // [y: 8192*1024][gate: 8192*8]
  char* ws = (char*)d_ws;

  int*      ctrl = (int*)(ws + WS_CTRL);
  int*      tope = (int*)(ws + WS_TOPE);
  float*    topw = (float*)(ws + WS_TOPW);
  int*      ptok = (int*)(ws + WS_PTOK);
  int*      arow = (int*)(ws + WS_AROW);
  uint16_t* xb   = (uint16_t*)(ws + WS_XB);
  uint16_t* w1t  = (uint16_t*)(ws + WS_W1T);
  uint16_t* w2t  = (uint16_t*)(ws + WS_W2T);
  uint16_t* hbuf = (uint16_t*)(ws + WS_H);
  uint16_t* yeb  = (uint16_t*)(ws + WS_YE);        // overlays xb+w1t (dead by then)

  convw_kernel<<<dim3(16,16,16), 256, 0, stream>>>(W1, W2, w1t, w2t);
  gateconv_kernel<<<2048, 256, 0, stream>>>(x, Wg, bg, out + (size_t)TOKENS*DIM,
                                            tope, topw, xb);
  route_kernel<<<1, 1024, 0, stream>>>(tope, ctrl, ptok, arow);

  // worst-case m-tiles: sum ceil(cnt_e/128) <= 128 + 8 = 136; 8 N-tiles interleaved
  gemm1_kernel<<<136*8, 256, 0, stream>>>(xb, w1t, b1, ctrl, ptok, hbuf);
  gemm2_kernel<<<136*8, 256, 0, stream>>>(hbuf, w2t, b2, ctrl, yeb);
  combine_kernel<<<TOKENS, 256, 0, stream>>>(yeb, arow, topw, out);
}

// Round 5
// 275.883 us; speedup vs baseline: 2.1805x; 1.0638x over previous
//
#include <hip/hip_runtime.h>
#include <stdint.h>

#define TOKENS 8192
#define DIM    1024
#define NEXP   8
#define NASSIGN (TOKENS*2)
#define BK     64          // K-depth of LDS tile (32 KB total LDS)

// ---- control block indices (ints) ----
#define C_ROW   16   // 9: per-expert row prefix (row_start), [8]=16384
#define C_TILE  25   // 9: per-expert m-tile prefix
#define C_TOTAL 34   // total m-tiles

// ---- workspace layout (bytes) ----
#define WS_CTRL  0
#define WS_TOPE  1024
#define WS_TOPW  (WS_TOPE + NASSIGN*4)
#define WS_PTOK  (WS_TOPW + NASSIGN*4)
#define WS_AROW  (WS_PTOK + NASSIGN*4)
#define WS_XB    (WS_AROW + NASSIGN*4)                 // 263168, 256-aligned
#define WS_W1T   (WS_XB  + (size_t)TOKENS*DIM*2)
#define WS_W2T   (WS_W1T + (size_t)NEXP*DIM*DIM*2)
#define WS_H     (WS_W2T + (size_t)NEXP*DIM*DIM*2)
// ye (bf16, 16384x1024 = 32 MiB) overlays xb+w1t, both dead by gemm2 time:
#define WS_YE    WS_XB

#define WGLD (DIM + 4)   // padded LDS row for Wg^T staging (bank-conflict-free)

typedef __attribute__((ext_vector_type(8))) short short8;
typedef __attribute__((ext_vector_type(4))) float floatx4;

__device__ __forceinline__ uint32_t bfr(float f) {   // fp32 -> bf16 bits, RNE
  uint32_t v = __float_as_uint(f);
  return (v + 0x7FFFu + ((v >> 16) & 1u)) >> 16;
}
__device__ __forceinline__ float b2f(uint32_t u) { return __uint_as_float(u << 16); }

__device__ __forceinline__ void load_lds16(const void* g, void* l) {
  __builtin_amdgcn_global_load_lds(
      (const __attribute__((address_space(1))) uint32_t*)g,
      (__attribute__((address_space(3))) uint32_t*)l, 16, 0, 0);
}

// ---------------- fused gating + x->bf16 conversion (NO atomics) ----------------
__global__ __launch_bounds__(256) void gateconv_kernel(
    const float* __restrict__ x, const float* __restrict__ Wg,
    const float* __restrict__ bg, float* __restrict__ gate_out,
    int* __restrict__ top_e, float* __restrict__ top_w,
    uint16_t* __restrict__ xb) {
  __shared__ float wgs[NEXP * WGLD];   // wgs[e*WGLD + d] = Wg[d][e]
  int t = threadIdx.x;
  #pragma unroll
  for (int k = 0; k < 32; k++) {
    int i = k * 256 + t;               // coalesced read of Wg flat
    float v = Wg[i];
    wgs[(i & 7) * WGLD + (i >> 3)] = v;   // bank = 4*(i&7)+(i>>3): 2-way, free
  }
  __syncthreads();

  int wave = t >> 6, lane = t & 63;
  int tok = blockIdx.x * 4 + wave;
  const float4* xr = (const float4*)(x + (size_t)tok * DIM);
  uint2* xw = (uint2*)(xb + (size_t)tok * DIM);

  float4 acc[NEXP];
  #pragma unroll
  for (int e = 0; e < NEXP; e++) acc[e] = make_float4(0.f, 0.f, 0.f, 0.f);

  #pragma unroll
  for (int c = 0; c < 4; c++) {
    float4 xv = xr[c * 64 + lane];
    uint2 o;
    o.x = bfr(xv.x) | (bfr(xv.y) << 16);
    o.y = bfr(xv.z) | (bfr(xv.w) << 16);
    xw[c * 64 + lane] = o;
    int d0 = (c * 64 + lane) * 4;
    #pragma unroll
    for (int e = 0; e < NEXP; e++) {
      float4 wv = *(const float4*)&wgs[e * WGLD + d0];
      acc[e].x = fmaf(xv.x, wv.x, acc[e].x);
      acc[e].y = fmaf(xv.y, wv.y, acc[e].y);
      acc[e].z = fmaf(xv.z, wv.z, acc[e].z);
      acc[e].w = fmaf(xv.w, wv.w, acc[e].w);
    }
  }
  float s[NEXP];
  #pragma unroll
  for (int e = 0; e < NEXP; e++) s[e] = (acc[e].x + acc[e].y) + (acc[e].z + acc[e].w);
  #pragma unroll
  for (int off = 32; off > 0; off >>= 1) {
    #pragma unroll
    for (int e = 0; e < NEXP; e++) s[e] += __shfl_xor(s[e], off);
  }
  if (lane == 0) {
    float lg[NEXP], p[NEXP];
    float mx = -1e30f;
    #pragma unroll
    for (int e = 0; e < NEXP; e++) { lg[e] = s[e] + bg[e]; mx = fmaxf(mx, lg[e]); }
    float sum = 0.f;
    #pragma unroll
    for (int e = 0; e < NEXP; e++) { p[e] = expf(lg[e] - mx); sum += p[e]; }
    float inv = 1.f / sum;
    #pragma unroll
    for (int e = 0; e < NEXP; e++) p[e] *= inv;
    float4* go = (float4*)(gate_out + (size_t)tok * NEXP);
    go[0] = make_float4(p[0], p[1], p[2], p[3]);
    go[1] = make_float4(p[4], p[5], p[6], p[7]);
    int i1 = 0;
    #pragma unroll
    for (int e = 1; e < NEXP; e++) if (p[e] > p[i1]) i1 = e;
    int i2 = (i1 == 0) ? 1 : 0;
    #pragma unroll
    for (int e = 0; e < NEXP; e++) if (e != i1 && p[e] > p[i2]) i2 = e;
    float ev = expf(p[i2] - p[i1]);            // softmax over the two top probs
    float w1 = 1.f / (1.f + ev), w2 = ev / (1.f + ev);
    top_e[2*tok]   = i1; top_e[2*tok+1] = i2;
    top_w[2*tok]   = w1; top_w[2*tok+1] = w2;
  }
}

// transpose+convert: WT[e][f][d] = bf16(W[e][d][f]); 16 matrices (8 W1 + 8 W2)
__global__ void convw_kernel(const float* __restrict__ W1, const float* __restrict__ W2,
                             uint16_t* __restrict__ W1T, uint16_t* __restrict__ W2T) {
  __shared__ uint16_t tile[64][68];
  int m = blockIdx.z;
  const float* src = (m < 8) ? (W1 + (size_t)m*DIM*DIM) : (W2 + (size_t)(m-8)*DIM*DIM);
  uint16_t*    dst = (m < 8) ? (W1T + (size_t)m*DIM*DIM) : (W2T + (size_t)(m-8)*DIM*DIM);
  int d0 = blockIdx.y * 64, f0 = blockIdx.x * 64;
  int t = threadIdx.x;
  int col = t & 63, rb = (t >> 6) * 16;
  #pragma unroll
  for (int i = 0; i < 16; i++) {
    int dr = rb + i;
    tile[dr][col] = (uint16_t)bfr(src[(size_t)(d0+dr)*DIM + f0 + col]);
  }
  __syncthreads();
  int dg = t & 15, frb = t >> 4;       // 4 bf16 along d per thread, 16 f-rows/pass
  #pragma unroll
  for (int i = 0; i < 4; i++) {
    int fr = frb + i * 16;
    uint32_t b0 = tile[dg*4+0][fr], b1 = tile[dg*4+1][fr];
    uint32_t b2 = tile[dg*4+2][fr], b3 = tile[dg*4+3][fr];
    uint2 v;
    v.x = b0 | (b1 << 16);
    v.y = b2 | (b3 << 16);
    *(uint2*)&dst[(size_t)(f0+fr)*DIM + d0 + dg*4] = v;
  }
}

// ---------------- deterministic routing: histogram + scan + scatter, 1 block ----------------
__global__ __launch_bounds__(1024) void route_kernel(
    const int* __restrict__ top_e, int* __restrict__ ctrl,
    int* __restrict__ ptok, int* __restrict__ arow) {
  __shared__ int sc[NEXP * 1024];      // 32 KB: per-thread per-expert counts -> excl prefix
  __shared__ int scnt[NEXP];           // per-expert totals
  __shared__ int rowstart[NEXP];
  int t = threadIdx.x;
  int e_loc[16];
  int cnt[NEXP];
  #pragma unroll
  for (int e = 0; e < NEXP; e++) cnt[e] = 0;
  #pragma unroll
  for (int j = 0; j < 16; j++) {
    int e = top_e[t * 16 + j];
    e_loc[j] = e;
    cnt[e]++;
  }
  #pragma unroll
  for (int e = 0; e < NEXP; e++) sc[e * 1024 + t] = cnt[e];
  __syncthreads();
  int wave = t >> 6, lane = t & 63;
  if (wave < NEXP) {                   // wave w: exclusive scan of expert w's 1024 counts
    int running = 0;
    for (int chunk = 0; chunk < 16; chunk++) {
      int idx = wave * 1024 + chunk * 64 + lane;
      int v = sc[idx];
      int incl = v;
      #pragma unroll
      for (int off = 1; off < 64; off <<= 1) {
        int u = __shfl_up(incl, off);
        if (lane >= off) incl += u;
      }
      sc[idx] = running + incl - v;    // exclusive prefix
      running += __shfl(incl, 63);
    }
    if (lane == 0) scnt[wave] = running;
  }
  __syncthreads();
  if (t == 0) {
    int rs = 0, ts = 0;
    for (int e = 0; e < NEXP; e++) {
      ctrl[C_ROW + e] = rs;
      ctrl[C_TILE + e] = ts;
      rowstart[e] = rs;
      int c = scnt[e];
      rs += c;
      ts += (c + 127) >> 7;
    }
    ctrl[C_ROW + NEXP] = rs;
    ctrl[C_TILE + NEXP] = ts;
    ctrl[C_TOTAL] = ts;
  }
  __syncthreads();
  int off[NEXP];
  #pragma unroll
  for (int e = 0; e < NEXP; e++) off[e] = rowstart[e] + sc[e * 1024 + t];
  #pragma unroll
  for (int j = 0; j < 16; j++) {
    int i = t * 16 + j;
    int e = e_loc[j];
    int pos = off[e]++;
    ptok[pos] = i >> 1;
    arow[i] = pos;                     // inverse permutation: assignment -> row
  }
}

// ---------------- GEMM block schedule ----------------
// Round-robin dispatch puts blockIdx.x % 8 on XCD (blockIdx.x & 7) [heuristic].
// XCD k owns m-tiles [17k, 17k+17), iterating n fastest: the 8 blocks sharing one
// A-tile run concurrently on ONE XCD (A L2-hit); B working set/XCD ~1-2 experts
// (2-4 MB, L2-resident). gemm1 & gemm2 share the map so h tiles written by gemm1
// are re-read by gemm2 from the same XCD's L2.
__device__ __forceinline__ bool sched_map(const int* ctrl, int bid,
                                          int& mtile, int& n0) {
  int xcd = bid & 7, j = bid >> 3;
  mtile = xcd * 17 + (j >> 3);
  n0 = (j & 7) * 128;
  return mtile < ctrl[C_TOTAL];
}

// ---------------- GEMM1: h = relu(gather(x) @ W1 + b1), bf16 out ----------------
__global__ __launch_bounds__(256, 2) void gemm1_kernel(
    const uint16_t* __restrict__ xb, const uint16_t* __restrict__ w1t,
    const float* __restrict__ b1, const int* __restrict__ ctrl,
    const int* __restrict__ ptok, uint16_t* __restrict__ h) {
  __shared__ __align__(16) uint16_t As[128*BK];
  __shared__ __align__(16) uint16_t Bs[128*BK];
  int mtile, n0;
  if (!sched_map(ctrl, blockIdx.x, mtile, n0)) return;
  int e = 0;
  #pragma unroll
  for (int k = 1; k < NEXP; k++) if (mtile >= ctrl[C_TILE + k]) e = k;
  int row0 = ctrl[C_ROW + e] + (mtile - ctrl[C_TILE + e]) * 128;
  int rend = ctrl[C_ROW + e + 1];

  int t = threadIdx.x, lane = t & 63, w = t >> 6;
  const uint16_t* gA[4];
  const uint16_t* gB[4];
  #pragma unroll
  for (int i = 0; i < 4; i++) {
    int s = i * 256 + t;               // LDS slot (16B units), 1024 per matrix
    int row = s >> 3, cs = s & 7;
    int gc = cs ^ (row & 7);           // inverse XOR swizzle applied at the source
    int ar = row0 + row; if (ar > NASSIGN-1) ar = NASSIGN-1;
    int tok = ptok[ar];
    gA[i] = xb  + (size_t)tok * DIM + gc*8;
    gB[i] = w1t + (size_t)e*DIM*DIM + (size_t)(n0 + row)*DIM + gc*8;
  }
  floatx4 acc[4][4];
  #pragma unroll
  for (int mi = 0; mi < 4; mi++)
    #pragma unroll
    for (int ni = 0; ni < 4; ni++) acc[mi][ni] = (floatx4)(0.f);

  int wm = w & 1, wn = w >> 1;
  int l15 = lane & 15, lq = lane >> 4;

  for (int kt = 0; kt < DIM/BK; kt++) {
    #pragma unroll
    for (int i = 0; i < 4; i++) {
      load_lds16(gA[i], &As[(i*256 + t) * 8]);
      load_lds16(gB[i], &Bs[(i*256 + t) * 8]);
      gA[i] += BK; gB[i] += BK;
    }
    __syncthreads();
    #pragma unroll
    for (int ks = 0; ks < 2; ks++) {
      short8 a[4], b[4];
      #pragma unroll
      for (int mi = 0; mi < 4; mi++) {
        int row = wm*64 + mi*16 + l15;
        int slot = (ks*4 + lq) ^ (row & 7);
        a[mi] = *(const short8*)&As[row*BK + slot*8];
      }
      #pragma unroll
      for (int ni = 0; ni < 4; ni++) {
        int row = wn*64 + ni*16 + l15;
        int slot = (ks*4 + lq) ^ (row & 7);
        b[ni] = *(const short8*)&Bs[row*BK + slot*8];
      }
      #pragma unroll
      for (int mi = 0; mi < 4; mi++)
        #pragma unroll
        for (int ni = 0; ni < 4; ni++)
          acc[mi][ni] = __builtin_amdgcn_mfma_f32_16x16x32_bf16(a[mi], b[ni], acc[mi][ni], 0, 0, 0);
    }
    __syncthreads();
  }
  #pragma unroll
  for (int mi = 0; mi < 4; mi++) {
    #pragma unroll
    for (int r = 0; r < 4; r++) {
      int rt = wm*64 + mi*16 + lq*4 + r;
      int ar = row0 + rt;
      if (ar < rend) {
        #pragma unroll
        for (int ni = 0; ni < 4; ni++) {
          int n = n0 + wn*64 + ni*16 + l15;
          float v = acc[mi][ni][r] + b1[e*DIM + n];
          v = fmaxf(v, 0.f);
          h[(size_t)ar*DIM + n] = (uint16_t)bfr(v);
        }
      }
    }
  }
}

// ---------------- GEMM2: ye = h @ W2 + b2, bf16 dense rows (no atomics) ----------------
__global__ __launch_bounds__(256, 2) void gemm2_kernel(
    const uint16_t* __restrict__ h, const uint16_t* __restrict__ w2t,
    const float* __restrict__ b2, const int* __restrict__ ctrl,
    uint16_t* __restrict__ yeb) {
  __shared__ __align__(16) uint16_t As[128*BK];
  __shared__ __align__(16) uint16_t Bs[128*BK];
  int mtile, n0;
  if (!sched_map(ctrl, blockIdx.x, mtile, n0)) return;
  int e = 0;
  #pragma unroll
  for (int k = 1; k < NEXP; k++) if (mtile >= ctrl[C_TILE + k]) e = k;
  int row0 = ctrl[C_ROW + e] + (mtile - ctrl[C_TILE + e]) * 128;
  int rend = ctrl[C_ROW + e + 1];

  int t = threadIdx.x, lane = t & 63, w = t >> 6;
  const uint16_t* gA[4];
  const uint16_t* gB[4];
  #pragma unroll
  for (int i = 0; i < 4; i++) {
    int s = i * 256 + t;
    int row = s >> 3, cs = s & 7;
    int gc = cs ^ (row & 7);
    int ar = row0 + row; if (ar > NASSIGN-1) ar = NASSIGN-1;
    gA[i] = h   + (size_t)ar * DIM + gc*8;
    gB[i] = w2t + (size_t)e*DIM*DIM + (size_t)(n0 + row)*DIM + gc*8;
  }
  floatx4 acc[4][4];
  #pragma unroll
  for (int mi = 0; mi < 4; mi++)
    #pragma unroll
    for (int ni = 0; ni < 4; ni++) acc[mi][ni] = (floatx4)(0.f);

  int wm = w & 1, wn = w >> 1;
  int l15 = lane & 15, lq = lane >> 4;

  for (int kt = 0; kt < DIM/BK; kt++) {
    #pragma unroll
    for (int i = 0; i < 4; i++) {
      load_lds16(gA[i], &As[(i*256 + t) * 8]);
      load_lds16(gB[i], &Bs[(i*256 + t) * 8]);
      gA[i] += BK; gB[i] += BK;
    }
    __syncthreads();
    #pragma unroll
    for (int ks = 0; ks < 2; ks++) {
      short8 a[4], b[4];
      #pragma unroll
      for (int mi = 0; mi < 4; mi++) {
        int row = wm*64 + mi*16 + l15;
        int slot = (ks*4 + lq) ^ (row & 7);
        a[mi] = *(const short8*)&As[row*BK + slot*8];
      }
      #pragma unroll
      for (int ni = 0; ni < 4; ni++) {
        int row = wn*64 + ni*16 + l15;
        int slot = (ks*4 + lq) ^ (row & 7);
        b[ni] = *(const short8*)&Bs[row*BK + slot*8];
      }
      #pragma unroll
      for (int mi = 0; mi < 4; mi++)
        #pragma unroll
        for (int ni = 0; ni < 4; ni++)
          acc[mi][ni] = __builtin_amdgcn_mfma_f32_16x16x32_bf16(a[mi], b[ni], acc[mi][ni], 0, 0, 0);
    }
    __syncthreads();
  }
  #pragma unroll
  for (int mi = 0; mi < 4; mi++) {
    #pragma unroll
    for (int r = 0; r < 4; r++) {
      int rt = wm*64 + mi*16 + lq*4 + r;
      int ar = row0 + rt;
      if (ar < rend) {
        #pragma unroll
        for (int ni = 0; ni < 4; ni++) {
          int n = n0 + wn*64 + ni*16 + l15;
          float v = acc[mi][ni][r] + b2[e*DIM + n];
          yeb[(size_t)ar*DIM + n] = (uint16_t)bfr(v);
        }
      }
    }
  }
}

// ---------------- combine: y[tok] = w0*ye[r0] + w1*ye[r1] ----------------
__global__ __launch_bounds__(256) void combine_kernel(
    const uint16_t* __restrict__ yeb, const int* __restrict__ arow,
    const float* __restrict__ top_w, float* __restrict__ y) {
  int tok = blockIdx.x, t = threadIdx.x;
  int r0 = arow[2*tok], r1 = arow[2*tok+1];
  float w0 = top_w[2*tok], w1 = top_w[2*tok+1];
  const uint2* a = (const uint2*)(yeb + (size_t)r0 * DIM);
  const uint2* b = (const uint2*)(yeb + (size_t)r1 * DIM);
  uint2 av = a[t], bv = b[t];
  float4 o;
  o.x = w0 * b2f(av.x & 0xFFFFu) + w1 * b2f(bv.x & 0xFFFFu);
  o.y = w0 * b2f(av.x >> 16)     + w1 * b2f(bv.x >> 16);
  o.z = w0 * b2f(av.y & 0xFFFFu) + w1 * b2f(bv.y & 0xFFFFu);
  o.w = w0 * b2f(av.y >> 16)     + w1 * b2f(bv.y >> 16);
  ((float4*)(y + (size_t)tok * DIM))[t] = o;
}

extern "C" void kernel_launch(void* const* d_in, const int* in_sizes, int n_in,
                              void* d_out, int out_size, void* d_ws, size_t ws_size,
                              hipStream_t stream) {
  const float* x  = (const float*)d_in[0];
  const float* Wg = (const float*)d_in[1];
  const float* bg = (const float*)d_in[2];
  const float* W1 = (const float*)d_in[3];
  const float* b1 = (const float*)d_in[4];
  const float* W2 = (const float*)d_in[5];
  const float* b2 = (const float*)d_in[6];
  float* out = (float*)d_out;                      // [y: 8192*1024][gate: 8192*8]
  char* ws = (char*)d_ws;

  int*      ctrl = (int*)(ws + WS_CTRL);
  int*      tope = (int*)(ws + WS_TOPE);
  float*    topw = (float*)(ws + WS_TOPW);
  int*      ptok = (int*)(ws + WS_PTOK);
  int*      arow = (int*)(ws + WS_AROW);
  uint16_t* xb   = (uint16_t*)(ws + WS_XB);
  uint16_t* w1t  = (uint16_t*)(ws + WS_W1T);
  uint16_t* w2t  = (uint16_t*)(ws + WS_W2T);
  uint16_t* hbuf = (uint16_t*)(ws + WS_H);
  uint16_t* yeb  = (uint16_t*)(ws + WS_YE);        // overlays xb+w1t (dead by then)

  convw_kernel<<<dim3(16,16,16), 256, 0, stream>>>(W1, W2, w1t, w2t);
  gateconv_kernel<<<2048, 256, 0, stream>>>(x, Wg, bg, out + (size_t)TOKENS*DIM,
                                            tope, topw, xb);
  route_kernel<<<1, 1024, 0, stream>>>(tope, ctrl, ptok, arow);

  // 136 m-tile slots x 8 n-tiles, XCD-chunked (see sched_map)
  gemm1_kernel<<<136*8, 256, 0, stream>>>(xb, w1t, b1, ctrl, ptok, hbuf);
  gemm2_kernel<<<136*8, 256, 0, stream>>>(hbuf, w2t, b2, ctrl, yeb);
  combine_kernel<<<TOKENS, 256, 0, stream>>>(yeb, arow, topw, out);
}

// Round 6
// 267.885 us; speedup vs baseline: 2.2456x; 1.0299x over previous
//
#include <hip/hip_runtime.h>
#include <stdint.h>

#define TOKENS 8192
#define DIM    1024
#define NEXP   8
#define NASSIGN (TOKENS*2)
#define BK     64          // K-depth of LDS tile (32 KB total LDS)

// ---- control block indices (ints) ----
#define C_ROW   16   // 9: per-expert row prefix (row_start), [8]=16384
#define C_TILE  25   // 9: per-expert m-tile prefix
#define C_TOTAL 34   // total m-tiles

// ---- workspace layout (bytes) ----
#define WS_CTRL  0
#define WS_TOPE  1024
#define WS_TOPW  (WS_TOPE + NASSIGN*4)
#define WS_PTOK  (WS_TOPW + NASSIGN*4)
#define WS_AROW  (WS_PTOK + NASSIGN*4)
#define WS_XB    (WS_AROW + NASSIGN*4)                 // 263168, 256-aligned
#define WS_W1T   (WS_XB  + (size_t)TOKENS*DIM*2)
#define WS_W2T   (WS_W1T + (size_t)NEXP*DIM*DIM*2)
#define WS_H     (WS_W2T + (size_t)NEXP*DIM*DIM*2)
// ye (bf16, 16384x1024 = 32 MiB) overlays xb+w1t, both dead by gemm2 time:
#define WS_YE    WS_XB

#define WGLD (DIM + 4)   // padded LDS row for Wg^T staging (bank-conflict-free)

typedef __attribute__((ext_vector_type(8))) short short8;
typedef __attribute__((ext_vector_type(4))) float floatx4;

__device__ __forceinline__ uint32_t bfr(float f) {   // fp32 -> bf16 bits, RNE
  uint32_t v = __float_as_uint(f);
  return (v + 0x7FFFu + ((v >> 16) & 1u)) >> 16;
}
__device__ __forceinline__ float b2f(uint32_t u) { return __uint_as_float(u << 16); }

__device__ __forceinline__ void load_lds16(const void* g, void* l) {
  __builtin_amdgcn_global_load_lds(
      (const __attribute__((address_space(1))) uint32_t*)g,
      (__attribute__((address_space(3))) uint32_t*)l, 16, 0, 0);
}

// ---------------- merged preprocessing: weight transpose + gating + x->bf16 ----
// Blocks [0, 2048): gating/convert-x (gateconv). Blocks [2048, 6144): convw.
// Merged so the HBM-bound transpose overlaps the mixed gating work in one dispatch.
__global__ __launch_bounds__(256) void prep_kernel(
    const float* __restrict__ x, const float* __restrict__ Wg,
    const float* __restrict__ bg, float* __restrict__ gate_out,
    int* __restrict__ top_e, float* __restrict__ top_w,
    uint16_t* __restrict__ xb,
    const float* __restrict__ W1, const float* __restrict__ W2,
    uint16_t* __restrict__ W1T, uint16_t* __restrict__ W2T) {
  __shared__ __align__(16) char smem[NEXP * WGLD * 4];   // 32.9 KB union
  int t = threadIdx.x;

  if (blockIdx.x >= 2048) {
    // ---------- convw: WT[e][f][d] = bf16(W[e][d][f]), 64x64 tiles ----------
    uint16_t (*tile)[68] = (uint16_t (*)[68])smem;
    int cb = blockIdx.x - 2048;            // 0..4095
    int m  = cb >> 8;                      // 16 matrices (8 W1 + 8 W2)
    int d0 = ((cb >> 4) & 15) * 64, f0 = (cb & 15) * 64;
    const float* src = (m < 8) ? (W1 + (size_t)m*DIM*DIM) : (W2 + (size_t)(m-8)*DIM*DIM);
    uint16_t*    dst = (m < 8) ? (W1T + (size_t)m*DIM*DIM) : (W2T + (size_t)(m-8)*DIM*DIM);
    int col = t & 63, rb = (t >> 6) * 16;
    #pragma unroll
    for (int i = 0; i < 16; i++) {
      int dr = rb + i;
      tile[dr][col] = (uint16_t)bfr(src[(size_t)(d0+dr)*DIM + f0 + col]);
    }
    __syncthreads();
    int dg = t & 15, frb = t >> 4;         // 4 bf16 along d per thread, 16 f-rows/pass
    #pragma unroll
    for (int i = 0; i < 4; i++) {
      int fr = frb + i * 16;
      uint32_t b0 = tile[dg*4+0][fr], b1 = tile[dg*4+1][fr];
      uint32_t b2 = tile[dg*4+2][fr], b3 = tile[dg*4+3][fr];
      uint2 v;
      v.x = b0 | (b1 << 16);
      v.y = b2 | (b3 << 16);
      *(uint2*)&dst[(size_t)(f0+fr)*DIM + d0 + dg*4] = v;
    }
    return;
  }

  // ---------- gateconv: 1 wave per token, 4 tokens/block ----------
  float* wgs = (float*)smem;               // wgs[e*WGLD + d] = Wg[d][e]
  #pragma unroll
  for (int k = 0; k < 32; k++) {
    int i = k * 256 + t;                   // coalesced read of Wg flat
    float v = Wg[i];
    wgs[(i & 7) * WGLD + (i >> 3)] = v;    // bank = 4*(i&7)+(i>>3): 2-way, free
  }
  __syncthreads();

  int wave = t >> 6, lane = t & 63;
  int tok = blockIdx.x * 4 + wave;
  const float4* xr = (const float4*)(x + (size_t)tok * DIM);
  uint2* xw = (uint2*)(xb + (size_t)tok * DIM);

  float4 acc[NEXP];
  #pragma unroll
  for (int e = 0; e < NEXP; e++) acc[e] = make_float4(0.f, 0.f, 0.f, 0.f);

  #pragma unroll
  for (int c = 0; c < 4; c++) {
    float4 xv = xr[c * 64 + lane];
    uint2 o;
    o.x = bfr(xv.x) | (bfr(xv.y) << 16);
    o.y = bfr(xv.z) | (bfr(xv.w) << 16);
    xw[c * 64 + lane] = o;
    int d0 = (c * 64 + lane) * 4;
    #pragma unroll
    for (int e = 0; e < NEXP; e++) {
      float4 wv = *(const float4*)&wgs[e * WGLD + d0];
      acc[e].x = fmaf(xv.x, wv.x, acc[e].x);
      acc[e].y = fmaf(xv.y, wv.y, acc[e].y);
      acc[e].z = fmaf(xv.z, wv.z, acc[e].z);
      acc[e].w = fmaf(xv.w, wv.w, acc[e].w);
    }
  }
  float s[NEXP];
  #pragma unroll
  for (int e = 0; e < NEXP; e++) s[e] = (acc[e].x + acc[e].y) + (acc[e].z + acc[e].w);
  #pragma unroll
  for (int off = 32; off > 0; off >>= 1) {
    #pragma unroll
    for (int e = 0; e < NEXP; e++) s[e] += __shfl_xor(s[e], off);
  }
  if (lane == 0) {
    float lg[NEXP], p[NEXP];
    float mx = -1e30f;
    #pragma unroll
    for (int e = 0; e < NEXP; e++) { lg[e] = s[e] + bg[e]; mx = fmaxf(mx, lg[e]); }
    float sum = 0.f;
    #pragma unroll
    for (int e = 0; e < NEXP; e++) { p[e] = expf(lg[e] - mx); sum += p[e]; }
    float inv = 1.f / sum;
    #pragma unroll
    for (int e = 0; e < NEXP; e++) p[e] *= inv;
    float4* go = (float4*)(gate_out + (size_t)tok * NEXP);
    go[0] = make_float4(p[0], p[1], p[2], p[3]);
    go[1] = make_float4(p[4], p[5], p[6], p[7]);
    int i1 = 0;
    #pragma unroll
    for (int e = 1; e < NEXP; e++) if (p[e] > p[i1]) i1 = e;
    int i2 = (i1 == 0) ? 1 : 0;
    #pragma unroll
    for (int e = 0; e < NEXP; e++) if (e != i1 && p[e] > p[i2]) i2 = e;
    float ev = expf(p[i2] - p[i1]);        // softmax over the two top probs
    float w1 = 1.f / (1.f + ev), w2 = ev / (1.f + ev);
    top_e[2*tok]   = i1; top_e[2*tok+1] = i2;
    top_w[2*tok]   = w1; top_w[2*tok+1] = w2;
  }
}

// ---------------- deterministic routing: histogram + scan + scatter, 1 block ----------------
__global__ __launch_bounds__(1024) void route_kernel(
    const int* __restrict__ top_e, int* __restrict__ ctrl,
    int* __restrict__ ptok, int* __restrict__ arow) {
  __shared__ int sc[NEXP * 1024];      // 32 KB: per-thread per-expert counts -> excl prefix
  __shared__ int scnt[NEXP];           // per-expert totals
  __shared__ int rowstart[NEXP];
  int t = threadIdx.x;
  int e_loc[16];
  int cnt[NEXP];
  #pragma unroll
  for (int e = 0; e < NEXP; e++) cnt[e] = 0;
  #pragma unroll
  for (int j = 0; j < 16; j++) {
    int e = top_e[t * 16 + j];
    e_loc[j] = e;
    cnt[e]++;
  }
  #pragma unroll
  for (int e = 0; e < NEXP; e++) sc[e * 1024 + t] = cnt[e];
  __syncthreads();
  int wave = t >> 6, lane = t & 63;
  if (wave < NEXP) {                   // wave w: exclusive scan of expert w's 1024 counts
    int running = 0;
    for (int chunk = 0; chunk < 16; chunk++) {
      int idx = wave * 1024 + chunk * 64 + lane;
      int v = sc[idx];
      int incl = v;
      #pragma unroll
      for (int off = 1; off < 64; off <<= 1) {
        int u = __shfl_up(incl, off);
        if (lane >= off) incl += u;
      }
      sc[idx] = running + incl - v;    // exclusive prefix
      running += __shfl(incl, 63);
    }
    if (lane == 0) scnt[wave] = running;
  }
  __syncthreads();
  if (t == 0) {
    int rs = 0, ts = 0;
    for (int e = 0; e < NEXP; e++) {
      ctrl[C_ROW + e] = rs;
      ctrl[C_TILE + e] = ts;
      rowstart[e] = rs;
      int c = scnt[e];
      rs += c;
      ts += (c + 127) >> 7;
    }
    ctrl[C_ROW + NEXP] = rs;
    ctrl[C_TILE + NEXP] = ts;
    ctrl[C_TOTAL] = ts;
  }
  __syncthreads();
  int off[NEXP];
  #pragma unroll
  for (int e = 0; e < NEXP; e++) off[e] = rowstart[e] + sc[e * 1024 + t];
  #pragma unroll
  for (int j = 0; j < 16; j++) {
    int i = t * 16 + j;
    int e = e_loc[j];
    int pos = off[e]++;
    ptok[pos] = i >> 1;
    arow[i] = pos;                     // inverse permutation: assignment -> row
  }
}

// ---------------- GEMM block schedule ----------------
// Round-robin dispatch puts blockIdx.x % 8 on XCD (blockIdx.x & 7) [heuristic].
// XCD k owns a contiguous, BALANCED span of ceil(total/8) m-tiles, iterating n
// fastest: the 8 blocks sharing one A-tile run concurrently on ONE XCD (A
// L2-hit); B working set/XCD ~1-2 experts (2-4 MB, L2-resident). gemm1 & gemm2
// share the map so h tiles written by gemm1 are re-read from the same XCD's L2.
__device__ __forceinline__ bool sched_map(const int* ctrl, int bid,
                                          int& mtile, int& n0) {
  int total = ctrl[C_TOTAL];           // 128..135
  int spx = (total + 7) >> 3;          // slots per XCD: 16 or 17
  int xcd = bid & 7, j = bid >> 3;
  int slot = j >> 3;
  if (slot >= spx) return false;
  mtile = xcd * spx + slot;
  n0 = (j & 7) * 128;
  return mtile < total;
}

// ---------------- GEMM1: h = relu(gather(x) @ W1 + b1), bf16 out ----------------
__global__ __launch_bounds__(256, 2) void gemm1_kernel(
    const uint16_t* __restrict__ xb, const uint16_t* __restrict__ w1t,
    const float* __restrict__ b1, const int* __restrict__ ctrl,
    const int* __restrict__ ptok, uint16_t* __restrict__ h) {
  __shared__ __align__(16) uint16_t As[128*BK];
  __shared__ __align__(16) uint16_t Bs[128*BK];
  int mtile, n0;
  if (!sched_map(ctrl, blockIdx.x, mtile, n0)) return;
  int e = 0;
  #pragma unroll
  for (int k = 1; k < NEXP; k++) if (mtile >= ctrl[C_TILE + k]) e = k;
  int row0 = ctrl[C_ROW + e] + (mtile - ctrl[C_TILE + e]) * 128;
  int rend = ctrl[C_ROW + e + 1];

  int t = threadIdx.x, lane = t & 63, w = t >> 6;
  const uint16_t* gA[4];
  const uint16_t* gB[4];
  #pragma unroll
  for (int i = 0; i < 4; i++) {
    int s = i * 256 + t;               // LDS slot (16B units), 1024 per matrix
    int row = s >> 3, cs = s & 7;
    int gc = cs ^ (row & 7);           // inverse XOR swizzle applied at the source
    int ar = row0 + row; if (ar > NASSIGN-1) ar = NASSIGN-1;
    int tok = ptok[ar];
    gA[i] = xb  + (size_t)tok * DIM + gc*8;
    gB[i] = w1t + (size_t)e*DIM*DIM + (size_t)(n0 + row)*DIM + gc*8;
  }
  floatx4 acc[4][4];
  #pragma unroll
  for (int mi = 0; mi < 4; mi++)
    #pragma unroll
    for (int ni = 0; ni < 4; ni++) acc[mi][ni] = (floatx4)(0.f);

  int wm = w & 1, wn = w >> 1;
  int l15 = lane & 15, lq = lane >> 4;

  for (int kt = 0; kt < DIM/BK; kt++) {
    #pragma unroll
    for (int i = 0; i < 4; i++) {
      load_lds16(gA[i], &As[(i*256 + t) * 8]);
      load_lds16(gB[i], &Bs[(i*256 + t) * 8]);
      gA[i] += BK; gB[i] += BK;
    }
    __syncthreads();
    #pragma unroll
    for (int ks = 0; ks < 2; ks++) {
      short8 a[4], b[4];
      #pragma unroll
      for (int mi = 0; mi < 4; mi++) {
        int row = wm*64 + mi*16 + l15;
        int slot = (ks*4 + lq) ^ (row & 7);
        a[mi] = *(const short8*)&As[row*BK + slot*8];
      }
      #pragma unroll
      for (int ni = 0; ni < 4; ni++) {
        int row = wn*64 + ni*16 + l15;
        int slot = (ks*4 + lq) ^ (row & 7);
        b[ni] = *(const short8*)&Bs[row*BK + slot*8];
      }
      #pragma unroll
      for (int mi = 0; mi < 4; mi++)
        #pragma unroll
        for (int ni = 0; ni < 4; ni++)
          acc[mi][ni] = __builtin_amdgcn_mfma_f32_16x16x32_bf16(a[mi], b[ni], acc[mi][ni], 0, 0, 0);
    }
    __syncthreads();
  }
  #pragma unroll
  for (int mi = 0; mi < 4; mi++) {
    #pragma unroll
    for (int r = 0; r < 4; r++) {
      int rt = wm*64 + mi*16 + lq*4 + r;
      int ar = row0 + rt;
      if (ar < rend) {
        #pragma unroll
        for (int ni = 0; ni < 4; ni++) {
          int n = n0 + wn*64 + ni*16 + l15;
          float v = acc[mi][ni][r] + b1[e*DIM + n];
          v = fmaxf(v, 0.f);
          h[(size_t)ar*DIM + n] = (uint16_t)bfr(v);
        }
      }
    }
  }
}

// ---------------- GEMM2: ye = h @ W2 + b2, bf16 dense rows (no atomics) ----------------
__global__ __launch_bounds__(256, 2) void gemm2_kernel(
    const uint16_t* __restrict__ h, const uint16_t* __restrict__ w2t,
    const float* __restrict__ b2, const int* __restrict__ ctrl,
    uint16_t* __restrict__ yeb) {
  __shared__ __align__(16) uint16_t As[128*BK];
  __shared__ __align__(16) uint16_t Bs[128*BK];
  int mtile, n0;
  if (!sched_map(ctrl, blockIdx.x, mtile, n0)) return;
  int e = 0;
  #pragma unroll
  for (int k = 1; k < NEXP; k++) if (mtile >= ctrl[C_TILE + k]) e = k;
  int row0 = ctrl[C_ROW + e] + (mtile - ctrl[C_TILE + e]) * 128;
  int rend = ctrl[C_ROW + e + 1];

  int t = threadIdx.x, lane = t & 63, w = t >> 6;
  const uint16_t* gA[4];
  const uint16_t* gB[4];
  #pragma unroll
  for (int i = 0; i < 4; i++) {
    int s = i * 256 + t;
    int row = s >> 3, cs = s & 7;
    int gc = cs ^ (row & 7);
    int ar = row0 + row; if (ar > NASSIGN-1) ar = NASSIGN-1;
    gA[i] = h   + (size_t)ar * DIM + gc*8;
    gB[i] = w2t + (size_t)e*DIM*DIM + (size_t)(n0 + row)*DIM + gc*8;
  }
  floatx4 acc[4][4];
  #pragma unroll
  for (int mi = 0; mi < 4; mi++)
    #pragma unroll
    for (int ni = 0; ni < 4; ni++) acc[mi][ni] = (floatx4)(0.f);

  int wm = w & 1, wn = w >> 1;
  int l15 = lane & 15, lq = lane >> 4;

  for (int kt = 0; kt < DIM/BK; kt++) {
    #pragma unroll
    for (int i = 0; i < 4; i++) {
      load_lds16(gA[i], &As[(i*256 + t) * 8]);
      load_lds16(gB[i], &Bs[(i*256 + t) * 8]);
      gA[i] += BK; gB[i] += BK;
    }
    __syncthreads();
    #pragma unroll
    for (int ks = 0; ks < 2; ks++) {
      short8 a[4], b[4];
      #pragma unroll
      for (int mi = 0; mi < 4; mi++) {
        int row = wm*64 + mi*16 + l15;
        int slot = (ks*4 + lq) ^ (row & 7);
        a[mi] = *(const short8*)&As[row*BK + slot*8];
      }
      #pragma unroll
      for (int ni = 0; ni < 4; ni++) {
        int row = wn*64 + ni*16 + l15;
        int slot = (ks*4 + lq) ^ (row & 7);
        b[ni] = *(const short8*)&Bs[row*BK + slot*8];
      }
      #pragma unroll
      for (int mi = 0; mi < 4; mi++)
        #pragma unroll
        for (int ni = 0; ni < 4; ni++)
          acc[mi][ni] = __builtin_amdgcn_mfma_f32_16x16x32_bf16(a[mi], b[ni], acc[mi][ni], 0, 0, 0);
    }
    __syncthreads();
  }
  #pragma unroll
  for (int mi = 0; mi < 4; mi++) {
    #pragma unroll
    for (int r = 0; r < 4; r++) {
      int rt = wm*64 + mi*16 + lq*4 + r;
      int ar = row0 + rt;
      if (ar < rend) {
        #pragma unroll
        for (int ni = 0; ni < 4; ni++) {
          int n = n0 + wn*64 + ni*16 + l15;
          float v = acc[mi][ni][r] + b2[e*DIM + n];
          yeb[(size_t)ar*DIM + n] = (uint16_t)bfr(v);
        }
      }
    }
  }
}

// ---------------- combine: y[tok] = w0*ye[r0] + w1*ye[r1] ----------------
__global__ __launch_bounds__(256) void combine_kernel(
    const uint16_t* __restrict__ yeb, const int* __restrict__ arow,
    const float* __restrict__ top_w, float* __restrict__ y) {
  int tok = blockIdx.x, t = threadIdx.x;
  int r0 = arow[2*tok], r1 = arow[2*tok+1];
  float w0 = top_w[2*tok], w1 = top_w[2*tok+1];
  const uint2* a = (const uint2*)(yeb + (size_t)r0 * DIM);
  const uint2* b = (const uint2*)(yeb + (size_t)r1 * DIM);
  uint2 av = a[t], bv = b[t];
  float4 o;
  o.x = w0 * b2f(av.x & 0xFFFFu) + w1 * b2f(bv.x & 0xFFFFu);
  o.y = w0 * b2f(av.x >> 16)     + w1 * b2f(bv.x >> 16);
  o.z = w0 * b2f(av.y & 0xFFFFu) + w1 * b2f(bv.y & 0xFFFFu);
  o.w = w0 * b2f(av.y >> 16)     + w1 * b2f(bv.y >> 16);
  ((float4*)(y + (size_t)tok * DIM))[t] = o;
}

extern "C" void kernel_launch(void* const* d_in, const int* in_sizes, int n_in,
                              void* d_out, int out_size, void* d_ws, size_t ws_size,
                              hipStream_t stream) {
  const float* x  = (const float*)d_in[0];
  const float* Wg = (const float*)d_in[1];
  const float* bg = (const float*)d_in[2];
  const float* W1 = (const float*)d_in[3];
  const float* b1 = (const float*)d_in[4];
  const float* W2 = (const float*)d_in[5];
  const float* b2 = (const float*)d_in[6];
  float* out = (float*)d_out;                      // [y: 8192*1024][gate: 8192*8]
  char* ws = (char*)d_ws;

  int*      ctrl = (int*)(ws + WS_CTRL);
  int*      tope = (int*)(ws + WS_TOPE);
  float*    topw = (float*)(ws + WS_TOPW);
  int*      ptok = (int*)(ws + WS_PTOK);
  int*      arow = (int*)(ws + WS_AROW);
  uint16_t* xb   = (uint16_t*)(ws + WS_XB);
  uint16_t* w1t  = (uint16_t*)(ws + WS_W1T);
  uint16_t* w2t  = (uint16_t*)(ws + WS_W2T);
  uint16_t* hbuf = (uint16_t*)(ws + WS_H);
  uint16_t* yeb  = (uint16_t*)(ws + WS_YE);        // overlays xb+w1t (dead by then)

  // merged gating + x-convert + weight transpose (independent work, one dispatch)
  prep_kernel<<<6144, 256, 0, stream>>>(x, Wg, bg, out + (size_t)TOKENS*DIM,
                                        tope, topw, xb, W1, W2, w1t, w2t);
  route_kernel<<<1, 1024, 0, stream>>>(tope, ctrl, ptok, arow);

  // 17 m-slots x 8 XCDs x 8 n-tiles; sched_map balances slots via C_TOTAL
  gemm1_kernel<<<136*8, 256, 0, stream>>>(xb, w1t, b1, ctrl, ptok, hbuf);
  gemm2_kernel<<<136*8, 256, 0, stream>>>(hbuf, w2t, b2, ctrl, yeb);
  combine_kernel<<<TOKENS, 256, 0, stream>>>(yeb, arow, topw, out);
}